// Round 9
// baseline (234.342 us; speedup 1.0000x reference)
//
#include <hip/hip_runtime.h>
#include <stdint.h>

typedef unsigned short u16;
typedef __attribute__((ext_vector_type(8))) short bf16x8;
typedef __attribute__((ext_vector_type(4))) float f32x4;
typedef __attribute__((ext_vector_type(4))) unsigned int u32x4;
typedef __attribute__((ext_vector_type(2))) unsigned int u32x2;
typedef __attribute__((ext_vector_type(4))) unsigned short u16x4;

#define MFMA16(a, b, c) __builtin_amdgcn_mfma_f32_16x16x32_bf16(a, b, c, 0, 0, 0)
#define VMCNT(N) asm volatile("s_waitcnt vmcnt(" #N ")" ::: "memory")
#define LGKM0() asm volatile("s_waitcnt lgkmcnt(0)" ::: "memory")

__device__ __forceinline__ u16 f2bf(float f) {
  union { float f; uint32_t u; } v; v.f = f;
  uint32_t r = v.u + 0x7FFFu + ((v.u >> 16) & 1u);
  return (u16)(r >> 16);
}

__device__ __forceinline__ float bf2f(u16 u) {
  union { uint32_t u; float f; } v; v.u = ((uint32_t)u) << 16;
  return v.f;
}

__device__ __forceinline__ uint32_t cvt_pk_bf16(float a, float b) {
  uint32_t r;
  asm("v_cvt_pk_bf16_f32 %0, %1, %2" : "=v"(r) : "v"(a), "v"(b));
  return r;
}

// async global->LDS, 16B per lane. LDS dest is wave-uniform base + lane*16.
__device__ __forceinline__ void gload_lds16(const u16* g, u16* l) {
  __builtin_amdgcn_global_load_lds((const __attribute__((address_space(1))) void*)(g),
                                   (__attribute__((address_space(3))) void*)(l), 16, 0, 0);
}

// ---------------- LayerNorm: fp32 [rows][1024] -> bf16 [rows][1024] ----------------
__global__ __launch_bounds__(256) void ln_kernel(const float* __restrict__ x,
                                                 const float* __restrict__ g,
                                                 const float* __restrict__ beta,
                                                 u16* __restrict__ out) {
  int row = blockIdx.x;
  int tid = threadIdx.x;
  float4 v = ((const float4*)(x + (size_t)row * 1024))[tid];
  float s = v.x + v.y + v.z + v.w;
  float ss = v.x * v.x + v.y * v.y + v.z * v.z + v.w * v.w;
#pragma unroll
  for (int m = 1; m < 64; m <<= 1) { s += __shfl_xor(s, m); ss += __shfl_xor(ss, m); }
  __shared__ float red[8];
  int wave = tid >> 6, lane = tid & 63;
  if (lane == 0) { red[wave] = s; red[4 + wave] = ss; }
  __syncthreads();
  s = red[0] + red[1] + red[2] + red[3];
  ss = red[4] + red[5] + red[6] + red[7];
  float mean = s * (1.0f / 1024.0f);
  float var = ss * (1.0f / 1024.0f) - mean * mean;
  float rstd = rsqrtf(var + 1e-5f);
  float4 gv = ((const float4*)g)[tid];
  float4 bv = ((const float4*)beta)[tid];
  u16x4 o;
  o.x = f2bf((v.x - mean) * rstd * gv.x + bv.x);
  o.y = f2bf((v.y - mean) * rstd * gv.y + bv.y);
  o.z = f2bf((v.z - mean) * rstd * gv.z + bv.z);
  o.w = f2bf((v.w - mean) * rstd * gv.w + bv.w);
  *(u16x4*)(out + (size_t)row * 1024 + tid * 4) = o;
}

// ---- fused Wo-combine + LN2: out = x + bo + sum(p[z]); h2 = ln2(out) ----
__global__ __launch_bounds__(256) void combine_ln(const float* __restrict__ x,
                                                  const u16* __restrict__ p,
                                                  const float* __restrict__ bo,
                                                  const float* __restrict__ g,
                                                  const float* __restrict__ beta,
                                                  float* __restrict__ out,
                                                  u16* __restrict__ h2) {
  int row = blockIdx.x;
  int tid = threadIdx.x;
  size_t i = (size_t)row * 1024 + tid * 4;
  float4 v = *(const float4*)(x + i);
  float4 bb = *(const float4*)(bo + tid * 4);
  v.x += bb.x; v.y += bb.y; v.z += bb.z; v.w += bb.w;
#pragma unroll
  for (int z = 0; z < 4; z++) {
    u16x4 pv = *(const u16x4*)(p + (size_t)z * 4096 * 1024 + i);
    v.x += bf2f(pv.x); v.y += bf2f(pv.y); v.z += bf2f(pv.z); v.w += bf2f(pv.w);
  }
  *(float4*)(out + i) = v;
  float s = v.x + v.y + v.z + v.w;
  float ss = v.x * v.x + v.y * v.y + v.z * v.z + v.w * v.w;
#pragma unroll
  for (int m = 1; m < 64; m <<= 1) { s += __shfl_xor(s, m); ss += __shfl_xor(ss, m); }
  __shared__ float red[8];
  int wave = tid >> 6, lane = tid & 63;
  if (lane == 0) { red[wave] = s; red[4 + wave] = ss; }
  __syncthreads();
  s = red[0] + red[1] + red[2] + red[3];
  ss = red[4] + red[5] + red[6] + red[7];
  float mean = s * (1.0f / 1024.0f);
  float var = ss * (1.0f / 1024.0f) - mean * mean;
  float rstd = rsqrtf(var + 1e-5f);
  float4 gv = ((const float4*)g)[tid];
  float4 bv = ((const float4*)beta)[tid];
  u16x4 o;
  o.x = f2bf((v.x - mean) * rstd * gv.x + bv.x);
  o.y = f2bf((v.y - mean) * rstd * gv.y + bv.y);
  o.z = f2bf((v.z - mean) * rstd * gv.z + bv.z);
  o.w = f2bf((v.w - mean) * rstd * gv.w + bv.w);
  *(u16x4*)(h2 + i) = o;
}

// ------------- batched transpose: in fp32 [K][N] -> out bf16 [N][K] -------------
__global__ __launch_bounds__(256) void transpose_f32_bf16(const float* __restrict__ in,
                                                          u16* __restrict__ out,
                                                          int K, int N,
                                                          size_t in_bstride, size_t out_bstride) {
  __shared__ float tile[32][33];
  const float* I = in + (size_t)blockIdx.z * in_bstride;
  u16* O = out + (size_t)blockIdx.z * out_bstride;
  int n0 = blockIdx.x * 32, k0 = blockIdx.y * 32;
  int tx = threadIdx.x & 31, ty = threadIdx.x >> 5;  // ty 0..7
#pragma unroll
  for (int i = 0; i < 4; i++)
    tile[ty + i * 8][tx] = I[(size_t)(k0 + ty + i * 8) * N + n0 + tx];
  __syncthreads();
#pragma unroll
  for (int i = 0; i < 4; i++)
    O[(size_t)(n0 + ty + i * 8) * K + k0 + tx] = f2bf(tile[tx][ty + i * 8]);
}

// ---------------- 256x256 8-phase GEMM: C[M][N] = A[M][K] * Bt[N][K]^T ----------------
// m201-conformant schedule (see round 8). EP 0: QKV scatter; EP 2: relu+bias bf16;
// EP 4: bf16 split-K partial.
template <int EP>
__global__ __launch_bounds__(512, 2) void gemm8p(const u16* __restrict__ A,
                                                 const u16* __restrict__ Bt,
                                                 int M, int N, int K, int KS,
                                                 void* __restrict__ out0,
                                                 u16* __restrict__ out1,
                                                 u16* __restrict__ out2,
                                                 const float* __restrict__ bias) {
  __shared__ __align__(16) u16 lds[65536];  // A at 0, B at 32768 (u16 units)
  const int tid = threadIdx.x;
  const int lane = tid & 63, wave = tid >> 6;
  const int lo = lane & 15, hi = lane >> 4;
  const int wm = wave >> 2, wn = wave & 3;
  // XCD swizzle
  int gx = gridDim.x;
  int lin = blockIdx.y * gx + blockIdx.x;
  int nwg = gx * gridDim.y;
  int cpx = nwg >> 3;
  int swz = (lin & 7) * cpx + (lin >> 3);
  int bm0 = (swz / gx) * 256, bn0 = (swz % gx) * 256;
  int kbeg = blockIdx.z * KS;
  int T = KS >> 6;

  int rs_ = tid >> 3, ss_ = (tid & 7) ^ (rs_ & 7);
  const u16* srcA = A + (size_t)(bm0 + rs_) * K + kbeg + ss_ * 8;
  const u16* srcB = Bt + (size_t)(bn0 + rs_) * K + kbeg + ss_ * 8;
  const size_t i1 = (size_t)64 * K;
  const size_t h1 = (size_t)128 * K;
  const int dst0 = wave * 512;
  const int dst1 = 4096 + wave * 512;

  const int rpA = wm * 16 + lo;
  const int rpB = wn * 16 + lo;
  const int sp0 = (hi ^ (lo & 7)) * 8;

  f32x4 acc[8][4] = {};
  bf16x8 a[4][2], b0[2][2], b1[2][2];

  auto stageA = [&](int buf, int h, int koff) {
    const u16* s = srcA + koff + (h ? h1 : 0);
    u16* d = lds + (buf * 2 + h) * 8192;
    gload_lds16(s, d + dst0);
    gload_lds16(s + i1, d + dst1);
  };
  auto stageB = [&](int buf, int h, int koff) {
    const u16* s = srcB + koff + (h ? h1 : 0);
    u16* d = lds + 32768 + (buf * 2 + h) * 8192;
    gload_lds16(s, d + dst0);
    gload_lds16(s + i1, d + dst1);
  };
  auto loadA = [&](int buf, int h) {
    const u16* base = lds + (buf * 2 + h) * 8192 + rpA * 64;
#pragma unroll
    for (int m = 0; m < 4; m++) {
      a[m][0] = *(const bf16x8*)(base + m * 2048 + sp0);
      a[m][1] = *(const bf16x8*)(base + m * 2048 + (sp0 ^ 32));
    }
  };
  auto loadB = [&](bf16x8 (&bb)[2][2], int buf, int g) {
    const u16* base = lds + 32768 + (buf * 2 + g) * 8192 + rpB * 64;
#pragma unroll
    for (int n = 0; n < 2; n++) {
      bb[n][0] = *(const bf16x8*)(base + n * 4096 + sp0);
      bb[n][1] = *(const bf16x8*)(base + n * 4096 + (sp0 ^ 32));
    }
  };
  auto mmac = [&](int mh, int np, bf16x8 (&bb)[2][2]) {
    __builtin_amdgcn_s_setprio(1);
#pragma unroll
    for (int m = 0; m < 4; m++)
#pragma unroll
      for (int n = 0; n < 2; n++) {
        acc[mh + m][np + n] = MFMA16(a[m][0], bb[n][0], acc[mh + m][np + n]);
        acc[mh + m][np + n] = MFMA16(a[m][1], bb[n][1], acc[mh + m][np + n]);
      }
    __builtin_amdgcn_s_setprio(0);
  };

  stageA(0, 0, 0); stageB(0, 0, 0); stageB(0, 1, 0); stageA(0, 1, 0);
  VMCNT(4);
  __builtin_amdgcn_s_barrier();

  for (int t = 0; t < T; ++t) {
    int cur = t & 1, nxt = cur ^ 1;
    bool more = (t + 1 < T);
    int koff = (t + 1) * 64;
    // P1
    loadA(cur, 0); loadB(b0, cur, 0);
    if (more) stageA(nxt, 0, koff);
    __builtin_amdgcn_s_barrier();
    LGKM0();
    __builtin_amdgcn_sched_barrier(0);
    mmac(0, 0, b0);
    __builtin_amdgcn_s_barrier();
    // P2
    loadB(b1, cur, 1);
    if (more) { stageB(nxt, 0, koff); VMCNT(6); } else { VMCNT(2); }
    __builtin_amdgcn_s_barrier();
    LGKM0();
    __builtin_amdgcn_sched_barrier(0);
    mmac(0, 2, b1);
    __builtin_amdgcn_s_barrier();
    // P3
    loadA(cur, 1);
    if (more) { stageB(nxt, 1, koff); VMCNT(6); } else { VMCNT(0); }
    __builtin_amdgcn_s_barrier();
    LGKM0();
    __builtin_amdgcn_sched_barrier(0);
    mmac(4, 0, b0);
    __builtin_amdgcn_s_barrier();
    // P4
    if (more) { stageA(nxt, 1, koff); VMCNT(4); }
    __builtin_amdgcn_s_barrier();
    mmac(4, 2, b1);
    __builtin_amdgcn_s_barrier();
  }

  const int sec = (EP == 0) ? (bn0 >> 10) : 0;
#pragma unroll
  for (int mt = 0; mt < 8; mt++) {
    int gr0 = bm0 + (mt >> 2) * 128 + (mt & 3) * 32 + wm * 16 + hi * 4;
#pragma unroll
    for (int nt = 0; nt < 4; nt++) {
      int gc = bn0 + (nt >> 1) * 128 + (nt & 1) * 64 + wn * 16 + lo;
      if constexpr (EP == 0) {
        int b_ = gr0 >> 11, t_ = gr0 & 2047;
        int nn = gc & 1023, h_ = nn >> 6, e_ = nn & 63;
        size_t bh = (size_t)(b_ * 16 + h_);
        if (sec == 2) {  // vT: 4 consecutive t per thread -> one 8B store
          u32x2 w;
          w.x = cvt_pk_bf16(acc[mt][nt][0], acc[mt][nt][1]);
          w.y = cvt_pk_bf16(acc[mt][nt][2], acc[mt][nt][3]);
          *(u32x2*)(out2 + (bh * 64 + e_) * 2048 + t_) = w;
        } else {
          float sc = (sec == 0) ? 0.0450842200f : 1.0f;  // q pre-scale D^-0.5*log2e
          u16* dst = (sec == 0) ? (u16*)out0 : out1;
#pragma unroll
          for (int j = 0; j < 4; j++)
            dst[(bh * 2048 + t_ + j) * 64 + e_] = f2bf(acc[mt][nt][j] * sc);
        }
      } else {
#pragma unroll
        for (int j = 0; j < 4; j++) {
          int gr = gr0 + j;
          float val = acc[mt][nt][j];
          if constexpr (EP == 2) {
            float v = val + bias[gc];
            ((u16*)out0)[(size_t)gr * N + gc] = f2bf(fmaxf(v, 0.0f));
          } else if constexpr (EP == 4) {
            ((u16*)out0)[(size_t)blockIdx.z * M * N + (size_t)gr * N + gc] = f2bf(val);
          }
        }
      }
    }
  }
}

// -------- split-K=4 combine: out = res + bias + sum(p[z]) (p bf16, 4096x1024) --------
__global__ __launch_bounds__(256) void combine4(float* __restrict__ out,
                                                const float* __restrict__ res,
                                                const u16* __restrict__ p,
                                                const float* __restrict__ bias) {
  size_t i = ((size_t)blockIdx.x * 256 + threadIdx.x) * 4;
  float4 r = *(const float4*)(res + i);
  float4 bb = *(const float4*)(bias + (i & 1023));
  float a0 = r.x + bb.x, a1 = r.y + bb.y, a2 = r.z + bb.z, a3 = r.w + bb.w;
#pragma unroll
  for (int z = 0; z < 4; z++) {
    u16x4 v = *(const u16x4*)(p + (size_t)z * 4096 * 1024 + i);
    a0 += bf2f(v.x); a1 += bf2f(v.y); a2 += bf2f(v.z); a3 += bf2f(v.w);
  }
  float4 o4 = {a0, a1, a2, a3};
  *(float4*)(out + i) = o4;
}

// ------------------- causal flash attention, split-KV (uniform blocks) -------------------
// q (pre-scaled by D^-0.5*log2e), k: bf16 [B*H][T][64]; vt: bf16 [B*H][64][T].
// One block = 4 waves = one 64-row Q-tile x one KV-chunk of <=8 tiles (512 keys).
// Fixed-max softmax (m=0) => partials are additive: write O_partial (bf16 [64][64])
// and l_partial (fp32 [64]) per (bh, qtile, chunk); merge kernel sums and divides.
// blockIdx.x = u in [0,80): u<8: j=u,c=0 | u<24: j=8+(u-8)/2 | u<48: j=16+(u-24)/3
//                         | else: j=24+(u-48)/4. Chunk covers kv [8c, min(8c+8, j+1)).
__global__ __launch_bounds__(256) void attn_kernel(const u16* __restrict__ q,
                                                   const u16* __restrict__ k,
                                                   const u16* __restrict__ vt,
                                                   u16* __restrict__ po,
                                                   float* __restrict__ pl) {
  __shared__ __align__(16) u16 Ks[2][64 * 64];
  __shared__ __align__(16) u16 Vs[2][64 * 64];
  __shared__ __align__(16) u16 Ps[4][16 * 72];
  int bh = blockIdx.y;
  int u = blockIdx.x;
  int j, c;
  if (u < 8)       { j = u; c = 0; }
  else if (u < 24) { j = 8 + ((u - 8) >> 1); c = (u - 8) & 1; }
  else if (u < 48) { j = 16 + (u - 24) / 3; c = (u - 24) % 3; }
  else             { j = 24 + ((u - 48) >> 2); c = (u - 48) & 3; }
  int kstart = c * 8;
  int kend = min(kstart + 8, j + 1);

  int tid = threadIdx.x, lane = tid & 63, wave = tid >> 6;
  int lo = lane & 15, hi = lane >> 4;
  const u16* qbase = q + (size_t)bh * 2048 * 64;
  const u16* kbase = k + (size_t)bh * 2048 * 64;
  const u16* vbase = vt + (size_t)bh * 64 * 2048;

  // staging: 256 thr x 2 chunks x 16B per matrix = one 64x64 bf16 tile
  int c0 = tid, c1 = tid + 256;
  int row0 = c0 >> 3, row1 = c1 >> 3;
  int sl0 = (c0 & 7) ^ (row0 & 7), sl1 = (c1 & 7) ^ (row1 & 7);
  int kOff0 = row0 * 64 + sl0 * 8, kOff1 = row1 * 64 + sl1 * 8;
  int vOff0 = row0 * 2048 + sl0 * 8, vOff1 = row1 * 2048 + sl1 * 8;

  int qrow = j * 64 + wave * 16 + lo;  // this lane's q-row (B-frag: n = lane&15)
  bf16x8 qf0 = *(const bf16x8*)(qbase + (size_t)qrow * 64 + hi * 8);
  bf16x8 qf1 = *(const bf16x8*)(qbase + (size_t)qrow * 64 + 32 + hi * 8);

  float l_r = 0.0f;
  f32x4 of[4] = {};
  u16* Pw = Ps[wave];

  auto stage = [&](int b, int kb) {
    gload_lds16(kbase + (size_t)kb * 4096 + kOff0, Ks[b] + wave * 512);
    gload_lds16(kbase + (size_t)kb * 4096 + kOff1, Ks[b] + 2048 + wave * 512);
    gload_lds16(vbase + kb * 64 + vOff0, Vs[b] + wave * 512);
    gload_lds16(vbase + kb * 64 + vOff1, Vs[b] + 2048 + wave * 512);
  };

  stage(0, kstart);
  __syncthreads();

  for (int kb = kstart; kb < kend; kb++) {
    int cur = (kb - kstart) & 1;
    if (kb + 1 < kend) stage(cur ^ 1, kb + 1);
    const u16* Kb = Ks[cur];
    const u16* Vb = Vs[cur];
    // S^T = K Q^T : D[key][q], key = nt*16 + hi*4 + jj, q = lo
    f32x4 s4[4] = {};
#pragma unroll
    for (int nt = 0; nt < 4; nt++) {
      int r = nt * 16 + lo, rw = r & 7;
      bf16x8 kf0 = *(const bf16x8*)(Kb + r * 64 + ((hi ^ rw) << 3));
      bf16x8 kf1 = *(const bf16x8*)(Kb + r * 64 + (((hi + 4) ^ rw) << 3));
      s4[nt] = MFMA16(kf0, qf0, s4[nt]);
      s4[nt] = MFMA16(kf1, qf1, s4[nt]);
    }
    float rs = 0.0f;
    bool diag = (kb == j);
#pragma unroll
    for (int nt = 0; nt < 4; nt++) {
      float e0, e1, e2, e3;
      if (diag) {
        int key = kb * 64 + nt * 16 + hi * 4;
        e0 = (key     > qrow) ? 0.0f : __builtin_amdgcn_exp2f(s4[nt][0]);
        e1 = (key + 1 > qrow) ? 0.0f : __builtin_amdgcn_exp2f(s4[nt][1]);
        e2 = (key + 2 > qrow) ? 0.0f : __builtin_amdgcn_exp2f(s4[nt][2]);
        e3 = (key + 3 > qrow) ? 0.0f : __builtin_amdgcn_exp2f(s4[nt][3]);
      } else {
        e0 = __builtin_amdgcn_exp2f(s4[nt][0]);
        e1 = __builtin_amdgcn_exp2f(s4[nt][1]);
        e2 = __builtin_amdgcn_exp2f(s4[nt][2]);
        e3 = __builtin_amdgcn_exp2f(s4[nt][3]);
      }
      rs += (e0 + e1) + (e2 + e3);
      u32x2 w;
      w.x = cvt_pk_bf16(e0, e1);
      w.y = cvt_pk_bf16(e2, e3);
      *(u32x2*)(Pw + lo * 72 + nt * 16 + hi * 4) = w;
    }
    rs += __shfl_xor(rs, 16);
    rs += __shfl_xor(rs, 32);
    l_r += rs;
    // O^T += Vt P^T : D[d][q], d = et*16 + hi*4 + jj, q = lo
    bf16x8 pb0 = *(const bf16x8*)(Pw + lo * 72 + hi * 8);
    bf16x8 pb1 = *(const bf16x8*)(Pw + lo * 72 + 32 + hi * 8);
#pragma unroll
    for (int et = 0; et < 4; et++) {
      int e = et * 16 + lo, ew = e & 7;
      bf16x8 v0 = *(const bf16x8*)(Vb + e * 64 + ((hi ^ ew) << 3));
      bf16x8 v1 = *(const bf16x8*)(Vb + e * 64 + (((hi + 4) ^ ew) << 3));
      of[et] = MFMA16(v0, pb0, of[et]);
      of[et] = MFMA16(v1, pb1, of[et]);
    }
    __syncthreads();
  }

  // write partials: po[((bh*32+j)*4+c)][qrow&63][d] bf16, pl[...][qrow&63] fp32
  size_t pbase = ((size_t)(bh * 32 + j) * 4 + c) * 4096;
  size_t obase = pbase + (size_t)(wave * 16 + lo) * 64 + hi * 4;
#pragma unroll
  for (int et = 0; et < 4; et++) {
    u32x2 w;
    w.x = cvt_pk_bf16(of[et][0], of[et][1]);
    w.y = cvt_pk_bf16(of[et][2], of[et][3]);
    *(u32x2*)(po + obase + et * 16) = w;
  }
  if (hi == 0) pl[(((size_t)(bh * 32 + j) * 4 + c) << 6) + wave * 16 + lo] = l_r;
}

// ---- attention merge: o[bb][t][hh*64+d] = sum_c O_c / sum_c l_c ----
// 4096 blocks x 256 thr; block covers 16 t-rows of one bh.
__global__ __launch_bounds__(256) void attn_merge(const u16* __restrict__ po,
                                                  const float* __restrict__ pl,
                                                  u16* __restrict__ o) {
  int bh = blockIdx.x >> 7;
  int t0 = (blockIdx.x & 127) * 16;
  int tid = threadIdx.x;
  int tt = tid >> 4, dd = (tid & 15) * 4;
  int t = t0 + tt;
  int j = t >> 6, tr = t & 63;
  int nc = (j >> 3) + 1;
  size_t pbase = ((size_t)(bh * 32 + j) * 4);
  float a0 = 0, a1 = 0, a2 = 0, a3 = 0, l = 0;
  for (int c = 0; c < nc; c++) {
    u16x4 v = *(const u16x4*)(po + (pbase + c) * 4096 + (size_t)tr * 64 + dd);
    a0 += bf2f(v.x); a1 += bf2f(v.y); a2 += bf2f(v.z); a3 += bf2f(v.w);
    l += pl[((pbase + c) << 6) + tr];
  }
  float inv = 1.0f / l;
  int hh = bh & 15, bb = bh >> 4;
  u32x2 w;
  w.x = cvt_pk_bf16(a0 * inv, a1 * inv);
  w.y = cvt_pk_bf16(a2 * inv, a3 * inv);
  *(u32x2*)(o + ((size_t)(bb * 2048 + t)) * 1024 + hh * 64 + dd) = w;
}

extern "C" void kernel_launch(void* const* d_in, const int* in_sizes, int n_in,
                              void* d_out, int out_size, void* d_ws, size_t ws_size,
                              hipStream_t stream) {
  const float* x = (const float*)d_in[0];
  const float* Wq = (const float*)d_in[1];
  const float* Wk = (const float*)d_in[2];
  const float* Wv = (const float*)d_in[3];
  const float* Wo = (const float*)d_in[4];
  const float* bo = (const float*)d_in[5];
  const float* W1 = (const float*)d_in[6];
  const float* b1 = (const float*)d_in[7];
  const float* W2 = (const float*)d_in[8];
  const float* b2 = (const float*)d_in[9];
  const float* g1 = (const float*)d_in[10];
  const float* be1 = (const float*)d_in[11];
  const float* g2 = (const float*)d_in[12];
  const float* be2 = (const float*)d_in[13];
  float* out = (float*)d_out;
  char* ws = (char*)d_ws;
  const size_t MB = 1024ull * 1024ull;

  // workspace map (78MB peak):
  //  0- 8 : h (ln1 out) -> o (attn-merge out)     [dead after Wo gemm]
  //  8-14 : BtQKV (3072x1024 bf16) -> WoT         [dead after Wo gemm]
  // 14-22 : qb        [dead after attn]
  // 22-30 : kb        [dead after attn]
  // 30-38 : vtb [dead after attn] -> h2 (combine_ln; dead after FFN1)
  // 38-71.5: po (attn O partials bf16)  [attn .. merge]
  // 71.5-73.5: pl (attn l partials fp32)[attn .. merge]
  // 38-46 : W1T -> W2T (written after combine_ln; po dead)
  // 46-78 : pwo (Wo bf16 partials 4x8MB) [Wo gemm .. combine_ln] -> yb (FFN1)
  //  0-32 : pf2 (FFN2 bf16 partials 4x8MB)
  u16* h = (u16*)(ws + 0);
  u16* o = h;
  u16* BtQKV = (u16*)(ws + 8 * MB);
  u16* WoT = BtQKV;
  u16* qb = (u16*)(ws + 14 * MB);
  u16* kb = (u16*)(ws + 22 * MB);
  u16* vtb = (u16*)(ws + 30 * MB);
  u16* h2 = vtb;
  u16* po = (u16*)(ws + 38 * MB);
  float* pl = (float*)(ws + 71 * MB + 512 * 1024);
  u16* W1T = (u16*)(ws + 38 * MB);
  u16* W2T = W1T;
  u16* pwo = (u16*)(ws + 46 * MB);
  u16* yb = (u16*)(ws + 46 * MB);
  u16* pf2 = (u16*)(ws + 0);

  // 1. LN1: x -> h (bf16)
  ln_kernel<<<4096, 256, 0, stream>>>(x, g1, be1, h);
  // 2. weight transposes for QKV (per-head [1024][64] -> [64][1024])
  transpose_f32_bf16<<<dim3(2, 32, 16), 256, 0, stream>>>(Wq, BtQKV, 1024, 64,
                                                          (size_t)1024 * 64, (size_t)64 * 1024);
  transpose_f32_bf16<<<dim3(2, 32, 16), 256, 0, stream>>>(Wk, BtQKV + 1024 * 1024, 1024, 64,
                                                          (size_t)1024 * 64, (size_t)64 * 1024);
  transpose_f32_bf16<<<dim3(2, 32, 16), 256, 0, stream>>>(Wv, BtQKV + 2048 * 1024, 1024, 64,
                                                          (size_t)1024 * 64, (size_t)64 * 1024);
  // 3. QKV projection: [4096][1024] x [3072][1024]^T, scatter epilogue (q pre-scaled)
  gemm8p<0><<<dim3(12, 16), 512, 0, stream>>>(h, BtQKV, 4096, 3072, 1024, 1024,
                                              (void*)qb, kb, vtb, nullptr);
  // 4. causal attention, split-KV: partials -> po/pl
  attn_kernel<<<dim3(80, 32), 256, 0, stream>>>(qb, kb, vtb, po, pl);
  // 4b. merge partials -> o (bf16 [B][T][D])
  attn_merge<<<4096, 256, 0, stream>>>(po, pl, o);
  // 5. Wo transpose
  transpose_f32_bf16<<<dim3(32, 32, 1), 256, 0, stream>>>(Wo, WoT, 1024, 1024, 0, 0);
  // 6. Wo split-K=4: bf16 partials = o@Wo -> pwo
  gemm8p<4><<<dim3(4, 16, 4), 512, 0, stream>>>(o, WoT, 4096, 1024, 1024, 256,
                                                (void*)pwo, nullptr, nullptr, nullptr);
  // 7. fused: out = x + bo + sum(pwo); h2 = ln2(out)
  combine_ln<<<4096, 256, 0, stream>>>(x, pwo, bo, g2, be2, out, h2);
  // 8. W1 transpose [1024][4096] -> [4096][1024]
  transpose_f32_bf16<<<dim3(128, 32, 1), 256, 0, stream>>>(W1, W1T, 1024, 4096, 0, 0);
  // 9. FFN1: y = relu(h2@W1 + b1) (bf16)
  gemm8p<2><<<dim3(16, 16), 512, 0, stream>>>(h2, W1T, 4096, 4096, 1024, 1024,
                                              (void*)yb, nullptr, nullptr, b1);
  // 10. W2 transpose [4096][1024] -> [1024][4096]
  transpose_f32_bf16<<<dim3(32, 128, 1), 256, 0, stream>>>(W2, W2T, 4096, 1024, 0, 0);
  // 11. FFN2 split-K=4: bf16 partials = y@W2 -> pf2
  gemm8p<4><<<dim3(4, 16, 4), 512, 0, stream>>>(yb, W2T, 4096, 1024, 4096, 1024,
                                                (void*)pf2, nullptr, nullptr, nullptr);
  // 12. out = x1 + b2 + sum(pf2)
  combine4<<<4096, 256, 0, stream>>>(out, out, pf2, b2);
}

// Round 10
// 228.293 us; speedup vs baseline: 1.0265x; 1.0265x over previous
//
#include <hip/hip_runtime.h>
#include <stdint.h>

typedef unsigned short u16;
typedef __attribute__((ext_vector_type(8))) short bf16x8;
typedef __attribute__((ext_vector_type(4))) float f32x4;
typedef __attribute__((ext_vector_type(4))) unsigned int u32x4;
typedef __attribute__((ext_vector_type(2))) unsigned int u32x2;
typedef __attribute__((ext_vector_type(4))) unsigned short u16x4;

#define MFMA16(a, b, c) __builtin_amdgcn_mfma_f32_16x16x32_bf16(a, b, c, 0, 0, 0)
#define VMCNT(N) asm volatile("s_waitcnt vmcnt(" #N ")" ::: "memory")
#define LGKM0() asm volatile("s_waitcnt lgkmcnt(0)" ::: "memory")

__device__ __forceinline__ u16 f2bf(float f) {
  union { float f; uint32_t u; } v; v.f = f;
  uint32_t r = v.u + 0x7FFFu + ((v.u >> 16) & 1u);
  return (u16)(r >> 16);
}

__device__ __forceinline__ float bf2f(u16 u) {
  union { uint32_t u; float f; } v; v.u = ((uint32_t)u) << 16;
  return v.f;
}

__device__ __forceinline__ uint32_t cvt_pk_bf16(float a, float b) {
  uint32_t r;
  asm("v_cvt_pk_bf16_f32 %0, %1, %2" : "=v"(r) : "v"(a), "v"(b));
  return r;
}

// async global->LDS, 16B per lane. LDS dest is wave-uniform base + lane*16.
__device__ __forceinline__ void gload_lds16(const u16* g, u16* l) {
  __builtin_amdgcn_global_load_lds((const __attribute__((address_space(1))) void*)(g),
                                   (__attribute__((address_space(3))) void*)(l), 16, 0, 0);
}

// ---------------- LayerNorm: fp32 [rows][1024] -> bf16 [rows][1024] ----------------
__global__ __launch_bounds__(256) void ln_kernel(const float* __restrict__ x,
                                                 const float* __restrict__ g,
                                                 const float* __restrict__ beta,
                                                 u16* __restrict__ out) {
  int row = blockIdx.x;
  int tid = threadIdx.x;
  float4 v = ((const float4*)(x + (size_t)row * 1024))[tid];
  float s = v.x + v.y + v.z + v.w;
  float ss = v.x * v.x + v.y * v.y + v.z * v.z + v.w * v.w;
#pragma unroll
  for (int m = 1; m < 64; m <<= 1) { s += __shfl_xor(s, m); ss += __shfl_xor(ss, m); }
  __shared__ float red[8];
  int wave = tid >> 6, lane = tid & 63;
  if (lane == 0) { red[wave] = s; red[4 + wave] = ss; }
  __syncthreads();
  s = red[0] + red[1] + red[2] + red[3];
  ss = red[4] + red[5] + red[6] + red[7];
  float mean = s * (1.0f / 1024.0f);
  float var = ss * (1.0f / 1024.0f) - mean * mean;
  float rstd = rsqrtf(var + 1e-5f);
  float4 gv = ((const float4*)g)[tid];
  float4 bv = ((const float4*)beta)[tid];
  u16x4 o;
  o.x = f2bf((v.x - mean) * rstd * gv.x + bv.x);
  o.y = f2bf((v.y - mean) * rstd * gv.y + bv.y);
  o.z = f2bf((v.z - mean) * rstd * gv.z + bv.z);
  o.w = f2bf((v.w - mean) * rstd * gv.w + bv.w);
  *(u16x4*)(out + (size_t)row * 1024 + tid * 4) = o;
}

// ---- fused Wo-combine + LN2: out = x + bo + sum(p[z]); h2 = ln2(out) ----
__global__ __launch_bounds__(256) void combine_ln(const float* __restrict__ x,
                                                  const u16* __restrict__ p,
                                                  const float* __restrict__ bo,
                                                  const float* __restrict__ g,
                                                  const float* __restrict__ beta,
                                                  float* __restrict__ out,
                                                  u16* __restrict__ h2) {
  int row = blockIdx.x;
  int tid = threadIdx.x;
  size_t i = (size_t)row * 1024 + tid * 4;
  float4 v = *(const float4*)(x + i);
  float4 bb = *(const float4*)(bo + tid * 4);
  v.x += bb.x; v.y += bb.y; v.z += bb.z; v.w += bb.w;
#pragma unroll
  for (int z = 0; z < 4; z++) {
    u16x4 pv = *(const u16x4*)(p + (size_t)z * 4096 * 1024 + i);
    v.x += bf2f(pv.x); v.y += bf2f(pv.y); v.z += bf2f(pv.z); v.w += bf2f(pv.w);
  }
  *(float4*)(out + i) = v;
  float s = v.x + v.y + v.z + v.w;
  float ss = v.x * v.x + v.y * v.y + v.z * v.z + v.w * v.w;
#pragma unroll
  for (int m = 1; m < 64; m <<= 1) { s += __shfl_xor(s, m); ss += __shfl_xor(ss, m); }
  __shared__ float red[8];
  int wave = tid >> 6, lane = tid & 63;
  if (lane == 0) { red[wave] = s; red[4 + wave] = ss; }
  __syncthreads();
  s = red[0] + red[1] + red[2] + red[3];
  ss = red[4] + red[5] + red[6] + red[7];
  float mean = s * (1.0f / 1024.0f);
  float var = ss * (1.0f / 1024.0f) - mean * mean;
  float rstd = rsqrtf(var + 1e-5f);
  float4 gv = ((const float4*)g)[tid];
  float4 bv = ((const float4*)beta)[tid];
  u16x4 o;
  o.x = f2bf((v.x - mean) * rstd * gv.x + bv.x);
  o.y = f2bf((v.y - mean) * rstd * gv.y + bv.y);
  o.z = f2bf((v.z - mean) * rstd * gv.z + bv.z);
  o.w = f2bf((v.w - mean) * rstd * gv.w + bv.w);
  *(u16x4*)(h2 + i) = o;
}

// ------------- batched transpose: in fp32 [K][N] -> out bf16 [N][K] -------------
__global__ __launch_bounds__(256) void transpose_f32_bf16(const float* __restrict__ in,
                                                          u16* __restrict__ out,
                                                          int K, int N,
                                                          size_t in_bstride, size_t out_bstride) {
  __shared__ float tile[32][33];
  const float* I = in + (size_t)blockIdx.z * in_bstride;
  u16* O = out + (size_t)blockIdx.z * out_bstride;
  int n0 = blockIdx.x * 32, k0 = blockIdx.y * 32;
  int tx = threadIdx.x & 31, ty = threadIdx.x >> 5;  // ty 0..7
#pragma unroll
  for (int i = 0; i < 4; i++)
    tile[ty + i * 8][tx] = I[(size_t)(k0 + ty + i * 8) * N + n0 + tx];
  __syncthreads();
#pragma unroll
  for (int i = 0; i < 4; i++)
    O[(size_t)(n0 + ty + i * 8) * K + k0 + tx] = f2bf(tile[tx][ty + i * 8]);
}

// ---- QKV weight transpose, 3 weights in one launch: z = w*16 + head ----
__global__ __launch_bounds__(256) void transpose_qkv3(const float* __restrict__ Wq,
                                                      const float* __restrict__ Wk,
                                                      const float* __restrict__ Wv,
                                                      u16* __restrict__ out) {
  __shared__ float tile[32][33];
  int w = blockIdx.z >> 4, head = blockIdx.z & 15;
  const float* src = (w == 0) ? Wq : (w == 1) ? Wk : Wv;
  const float* I = src + (size_t)head * 1024 * 64;
  u16* O = out + (size_t)w * 1024 * 1024 + (size_t)head * 64 * 1024;
  int n0 = blockIdx.x * 32, k0 = blockIdx.y * 32;
  int tx = threadIdx.x & 31, ty = threadIdx.x >> 5;
#pragma unroll
  for (int i = 0; i < 4; i++)
    tile[ty + i * 8][tx] = I[(size_t)(k0 + ty + i * 8) * 64 + n0 + tx];
  __syncthreads();
#pragma unroll
  for (int i = 0; i < 4; i++)
    O[(size_t)(n0 + ty + i * 8) * 1024 + k0 + tx] = f2bf(tile[tx][ty + i * 8]);
}

// ---------------- 256x256 8-phase GEMM: C[M][N] = A[M][K] * Bt[N][K]^T ----------------
// m201-conformant schedule (see round 8). EP 0: QKV scatter; EP 2: relu+bias bf16;
// EP 4: bf16 split-K partial.
template <int EP>
__global__ __launch_bounds__(512, 2) void gemm8p(const u16* __restrict__ A,
                                                 const u16* __restrict__ Bt,
                                                 int M, int N, int K, int KS,
                                                 void* __restrict__ out0,
                                                 u16* __restrict__ out1,
                                                 u16* __restrict__ out2,
                                                 const float* __restrict__ bias) {
  __shared__ __align__(16) u16 lds[65536];  // A at 0, B at 32768 (u16 units)
  const int tid = threadIdx.x;
  const int lane = tid & 63, wave = tid >> 6;
  const int lo = lane & 15, hi = lane >> 4;
  const int wm = wave >> 2, wn = wave & 3;
  // XCD swizzle
  int gx = gridDim.x;
  int lin = blockIdx.y * gx + blockIdx.x;
  int nwg = gx * gridDim.y;
  int cpx = nwg >> 3;
  int swz = (lin & 7) * cpx + (lin >> 3);
  int bm0 = (swz / gx) * 256, bn0 = (swz % gx) * 256;
  int kbeg = blockIdx.z * KS;
  int T = KS >> 6;

  int rs_ = tid >> 3, ss_ = (tid & 7) ^ (rs_ & 7);
  const u16* srcA = A + (size_t)(bm0 + rs_) * K + kbeg + ss_ * 8;
  const u16* srcB = Bt + (size_t)(bn0 + rs_) * K + kbeg + ss_ * 8;
  const size_t i1 = (size_t)64 * K;
  const size_t h1 = (size_t)128 * K;
  const int dst0 = wave * 512;
  const int dst1 = 4096 + wave * 512;

  const int rpA = wm * 16 + lo;
  const int rpB = wn * 16 + lo;
  const int sp0 = (hi ^ (lo & 7)) * 8;

  f32x4 acc[8][4] = {};
  bf16x8 a[4][2], b0[2][2], b1[2][2];

  auto stageA = [&](int buf, int h, int koff) {
    const u16* s = srcA + koff + (h ? h1 : 0);
    u16* d = lds + (buf * 2 + h) * 8192;
    gload_lds16(s, d + dst0);
    gload_lds16(s + i1, d + dst1);
  };
  auto stageB = [&](int buf, int h, int koff) {
    const u16* s = srcB + koff + (h ? h1 : 0);
    u16* d = lds + 32768 + (buf * 2 + h) * 8192;
    gload_lds16(s, d + dst0);
    gload_lds16(s + i1, d + dst1);
  };
  auto loadA = [&](int buf, int h) {
    const u16* base = lds + (buf * 2 + h) * 8192 + rpA * 64;
#pragma unroll
    for (int m = 0; m < 4; m++) {
      a[m][0] = *(const bf16x8*)(base + m * 2048 + sp0);
      a[m][1] = *(const bf16x8*)(base + m * 2048 + (sp0 ^ 32));
    }
  };
  auto loadB = [&](bf16x8 (&bb)[2][2], int buf, int g) {
    const u16* base = lds + 32768 + (buf * 2 + g) * 8192 + rpB * 64;
#pragma unroll
    for (int n = 0; n < 2; n++) {
      bb[n][0] = *(const bf16x8*)(base + n * 4096 + sp0);
      bb[n][1] = *(const bf16x8*)(base + n * 4096 + (sp0 ^ 32));
    }
  };
  auto mmac = [&](int mh, int np, bf16x8 (&bb)[2][2]) {
    __builtin_amdgcn_s_setprio(1);
#pragma unroll
    for (int m = 0; m < 4; m++)
#pragma unroll
      for (int n = 0; n < 2; n++) {
        acc[mh + m][np + n] = MFMA16(a[m][0], bb[n][0], acc[mh + m][np + n]);
        acc[mh + m][np + n] = MFMA16(a[m][1], bb[n][1], acc[mh + m][np + n]);
      }
    __builtin_amdgcn_s_setprio(0);
  };

  stageA(0, 0, 0); stageB(0, 0, 0); stageB(0, 1, 0); stageA(0, 1, 0);
  VMCNT(4);
  __builtin_amdgcn_s_barrier();

  for (int t = 0; t < T; ++t) {
    int cur = t & 1, nxt = cur ^ 1;
    bool more = (t + 1 < T);
    int koff = (t + 1) * 64;
    // P1
    loadA(cur, 0); loadB(b0, cur, 0);
    if (more) stageA(nxt, 0, koff);
    __builtin_amdgcn_s_barrier();
    LGKM0();
    __builtin_amdgcn_sched_barrier(0);
    mmac(0, 0, b0);
    __builtin_amdgcn_s_barrier();
    // P2
    loadB(b1, cur, 1);
    if (more) { stageB(nxt, 0, koff); VMCNT(6); } else { VMCNT(2); }
    __builtin_amdgcn_s_barrier();
    LGKM0();
    __builtin_amdgcn_sched_barrier(0);
    mmac(0, 2, b1);
    __builtin_amdgcn_s_barrier();
    // P3
    loadA(cur, 1);
    if (more) { stageB(nxt, 1, koff); VMCNT(6); } else { VMCNT(0); }
    __builtin_amdgcn_s_barrier();
    LGKM0();
    __builtin_amdgcn_sched_barrier(0);
    mmac(4, 0, b0);
    __builtin_amdgcn_s_barrier();
    // P4
    if (more) { stageA(nxt, 1, koff); VMCNT(4); }
    __builtin_amdgcn_s_barrier();
    mmac(4, 2, b1);
    __builtin_amdgcn_s_barrier();
  }

  const int sec = (EP == 0) ? (bn0 >> 10) : 0;
#pragma unroll
  for (int mt = 0; mt < 8; mt++) {
    int gr0 = bm0 + (mt >> 2) * 128 + (mt & 3) * 32 + wm * 16 + hi * 4;
#pragma unroll
    for (int nt = 0; nt < 4; nt++) {
      int gc = bn0 + (nt >> 1) * 128 + (nt & 1) * 64 + wn * 16 + lo;
      if constexpr (EP == 0) {
        int b_ = gr0 >> 11, t_ = gr0 & 2047;
        int nn = gc & 1023, h_ = nn >> 6, e_ = nn & 63;
        size_t bh = (size_t)(b_ * 16 + h_);
        if (sec == 2) {  // vT: 4 consecutive t per thread -> one 8B store
          u32x2 w;
          w.x = cvt_pk_bf16(acc[mt][nt][0], acc[mt][nt][1]);
          w.y = cvt_pk_bf16(acc[mt][nt][2], acc[mt][nt][3]);
          *(u32x2*)(out2 + (bh * 64 + e_) * 2048 + t_) = w;
        } else {
          float sc = (sec == 0) ? 0.0450842200f : 1.0f;  // q pre-scale D^-0.5*log2e
          u16* dst = (sec == 0) ? (u16*)out0 : out1;
#pragma unroll
          for (int j = 0; j < 4; j++)
            dst[(bh * 2048 + t_ + j) * 64 + e_] = f2bf(acc[mt][nt][j] * sc);
        }
      } else {
#pragma unroll
        for (int j = 0; j < 4; j++) {
          int gr = gr0 + j;
          float val = acc[mt][nt][j];
          if constexpr (EP == 2) {
            float v = val + bias[gc];
            ((u16*)out0)[(size_t)gr * N + gc] = f2bf(fmaxf(v, 0.0f));
          } else if constexpr (EP == 4) {
            ((u16*)out0)[(size_t)blockIdx.z * M * N + (size_t)gr * N + gc] = f2bf(val);
          }
        }
      }
    }
  }
}

// -------- split-K=4 combine: out = res + bias + sum(p[z]) (p bf16, 4096x1024) --------
__global__ __launch_bounds__(256) void combine4(float* __restrict__ out,
                                                const float* __restrict__ res,
                                                const u16* __restrict__ p,
                                                const float* __restrict__ bias) {
  size_t i = ((size_t)blockIdx.x * 256 + threadIdx.x) * 4;
  float4 r = *(const float4*)(res + i);
  float4 bb = *(const float4*)(bias + (i & 1023));
  float a0 = r.x + bb.x, a1 = r.y + bb.y, a2 = r.z + bb.z, a3 = r.w + bb.w;
#pragma unroll
  for (int z = 0; z < 4; z++) {
    u16x4 v = *(const u16x4*)(p + (size_t)z * 4096 * 1024 + i);
    a0 += bf2f(v.x); a1 += bf2f(v.y); a2 += bf2f(v.z); a3 += bf2f(v.w);
  }
  float4 o4 = {a0, a1, a2, a3};
  *(float4*)(out + i) = o4;
}

// ------------------ causal flash attention (adjacent paired Q-tiles) ------------------
// q (pre-scaled by D^-0.5*log2e), k: bf16 [B*H][T][64]; vt: bf16 [B*H][64][T];
// o: bf16 [B][T][1024]. Block u of 16 handles Q-tiles 2u [waves 0-3] and 2u+1
// [waves 4-7] sharing one double-buffered K/V staging pipeline over kv [0, 2u+2).
// Wave activity 97% (vs 67% for mirrored pairing); 272 stagings/bh (vs 392).
// Longest blocks dispatch first (u = 15 - blockIdx.x); 50KB LDS -> 3 blocks/CU.
// Swapped-operand MFMA: S^T = mfma(K,Q) puts a full q-row per lane; fixed-max
// softmax (m=0); P packed to LDS via v_cvt_pk_bf16_f32; O^T = mfma(Vt,P).
__global__ __launch_bounds__(512, 4) void attn_kernel(const u16* __restrict__ q,
                                                      const u16* __restrict__ k,
                                                      const u16* __restrict__ vt,
                                                      u16* __restrict__ o) {
  __shared__ __align__(16) u16 Ks[2][64 * 64];
  __shared__ __align__(16) u16 Vs[2][64 * 64];
  __shared__ __align__(16) u16 Ps[8][16 * 72];
  int bh = blockIdx.y;
  int u = (gridDim.x - 1) - blockIdx.x;     // 15..0: longest blocks first
  int tid = threadIdx.x, lane = tid & 63, wave = tid >> 6;
  int lo = lane & 15, hi = lane >> 4;
  int grp = wave >> 2;                      // 0: q-tile 2u, 1: q-tile 2u+1
  int qblk_w = 2 * u + grp;
  int qb0 = qblk_w * 64;
  int nkb = 2 * u + 2;                      // kv tiles needed by the longer tile
  const u16* qbase = q + (size_t)bh * 2048 * 64;
  const u16* kbase = k + (size_t)bh * 2048 * 64;
  const u16* vbase = vt + (size_t)bh * 64 * 2048;

  // staging geometry: 512 threads x 16B = one 64x64 bf16 tile per matrix
  int srow = tid >> 3;
  int ssl = (tid & 7) ^ (srow & 7);         // both-sides XOR swizzle (pre-swizzled src)
  int kOff = srow * 64 + ssl * 8;
  int vOff = srow * 2048 + ssl * 8;

  int qrow = qb0 + (wave & 3) * 16 + lo;    // this lane's q-row (B-frag: n = lane&15)
  bf16x8 qf0 = *(const bf16x8*)(qbase + (size_t)qrow * 64 + hi * 8);
  bf16x8 qf1 = *(const bf16x8*)(qbase + (size_t)qrow * 64 + 32 + hi * 8);

  float l_r = 0.0f;
  f32x4 of[4] = {};
  u16* Pw = Ps[wave];

  auto stage = [&](int b, int kb) {
    gload_lds16(kbase + (size_t)kb * 4096 + kOff, Ks[b] + wave * 512);
    gload_lds16(vbase + kb * 64 + vOff, Vs[b] + wave * 512);
  };

  stage(0, 0);
  __syncthreads();  // drains vmcnt

  for (int kb = 0; kb < nkb; kb++) {
    int cur = kb & 1;
    if (kb + 1 < nkb) stage(cur ^ 1, kb + 1);  // async prefetch of next tile
    if (kb <= qblk_w) {
      const u16* Kb = Ks[cur];
      const u16* Vb = Vs[cur];
      // S^T = K Q^T : D[key][q], key = nt*16 + hi*4 + jj, q = lo
      f32x4 s4[4] = {};
#pragma unroll
      for (int nt = 0; nt < 4; nt++) {
        int r = nt * 16 + lo, rw = r & 7;
        bf16x8 kf0 = *(const bf16x8*)(Kb + r * 64 + ((hi ^ rw) << 3));
        bf16x8 kf1 = *(const bf16x8*)(Kb + r * 64 + (((hi + 4) ^ rw) << 3));
        s4[nt] = MFMA16(kf0, qf0, s4[nt]);
        s4[nt] = MFMA16(kf1, qf1, s4[nt]);
      }
      // exp2 (fixed max) + row-sum; P -> LDS [q][key] packed 4-wide
      float rs = 0.0f;
      bool diag = (kb == qblk_w);
#pragma unroll
      for (int nt = 0; nt < 4; nt++) {
        float e0, e1, e2, e3;
        if (diag) {
          int key = kb * 64 + nt * 16 + hi * 4;
          e0 = (key     > qrow) ? 0.0f : __builtin_amdgcn_exp2f(s4[nt][0]);
          e1 = (key + 1 > qrow) ? 0.0f : __builtin_amdgcn_exp2f(s4[nt][1]);
          e2 = (key + 2 > qrow) ? 0.0f : __builtin_amdgcn_exp2f(s4[nt][2]);
          e3 = (key + 3 > qrow) ? 0.0f : __builtin_amdgcn_exp2f(s4[nt][3]);
        } else {
          e0 = __builtin_amdgcn_exp2f(s4[nt][0]);
          e1 = __builtin_amdgcn_exp2f(s4[nt][1]);
          e2 = __builtin_amdgcn_exp2f(s4[nt][2]);
          e3 = __builtin_amdgcn_exp2f(s4[nt][3]);
        }
        rs += (e0 + e1) + (e2 + e3);
        u32x2 w;
        w.x = cvt_pk_bf16(e0, e1);
        w.y = cvt_pk_bf16(e2, e3);
        *(u32x2*)(Pw + lo * 72 + nt * 16 + hi * 4) = w;
      }
      rs += __shfl_xor(rs, 16);
      rs += __shfl_xor(rs, 32);
      l_r += rs;
      // O^T += Vt P^T : D[d][q], d = et*16 + hi*4 + jj, q = lo
      bf16x8 pb0 = *(const bf16x8*)(Pw + lo * 72 + hi * 8);
      bf16x8 pb1 = *(const bf16x8*)(Pw + lo * 72 + 32 + hi * 8);
#pragma unroll
      for (int et = 0; et < 4; et++) {
        int e = et * 16 + lo, ew = e & 7;
        bf16x8 v0 = *(const bf16x8*)(Vb + e * 64 + ((hi ^ ew) << 3));
        bf16x8 v1 = *(const bf16x8*)(Vb + e * 64 + (((hi + 4) ^ ew) << 3));
        of[et] = MFMA16(v0, pb0, of[et]);
        of[et] = MFMA16(v1, pb1, of[et]);
      }
    }
    __syncthreads();  // next tile staged; all waves done with cur
  }
  // write O (q-row = lo, d contiguous in jj -> 8B packed stores)
  int hh = bh & 15, bb = bh >> 4;
  float inv = 1.0f / l_r;
  size_t obase = ((size_t)(bb * 2048 + qrow)) * 1024 + hh * 64 + hi * 4;
#pragma unroll
  for (int et = 0; et < 4; et++) {
    u32x2 w;
    w.x = cvt_pk_bf16(of[et][0] * inv, of[et][1] * inv);
    w.y = cvt_pk_bf16(of[et][2] * inv, of[et][3] * inv);
    *(u32x2*)(o + obase + et * 16) = w;
  }
}

extern "C" void kernel_launch(void* const* d_in, const int* in_sizes, int n_in,
                              void* d_out, int out_size, void* d_ws, size_t ws_size,
                              hipStream_t stream) {
  const float* x = (const float*)d_in[0];
  const float* Wq = (const float*)d_in[1];
  const float* Wk = (const float*)d_in[2];
  const float* Wv = (const float*)d_in[3];
  const float* Wo = (const float*)d_in[4];
  const float* bo = (const float*)d_in[5];
  const float* W1 = (const float*)d_in[6];
  const float* b1 = (const float*)d_in[7];
  const float* W2 = (const float*)d_in[8];
  const float* b2 = (const float*)d_in[9];
  const float* g1 = (const float*)d_in[10];
  const float* be1 = (const float*)d_in[11];
  const float* g2 = (const float*)d_in[12];
  const float* be2 = (const float*)d_in[13];
  float* out = (float*)d_out;
  char* ws = (char*)d_ws;
  const size_t MB = 1024ull * 1024ull;

  // workspace map (78MB peak):
  //  0- 8 : h (ln1 out) -> o (attn out)           [dead after Wo gemm]
  //  8-14 : BtQKV (3072x1024 bf16) -> WoT         [dead after Wo gemm]
  // 14-22 : qb        [dead after attn]
  // 22-30 : kb        [dead after attn]
  // 30-38 : vtb [dead after attn] -> h2 (combine_ln; dead after FFN1)
  // 38-46 : W1T -> W2T
  // 46-78 : pwo (Wo bf16 partials 4x8MB) [Wo gemm .. combine_ln] -> yb (FFN1)
  //  0-32 : pf2 (FFN2 bf16 partials 4x8MB)
  u16* h = (u16*)(ws + 0);
  u16* o = h;
  u16* BtQKV = (u16*)(ws + 8 * MB);
  u16* WoT = BtQKV;
  u16* qb = (u16*)(ws + 14 * MB);
  u16* kb = (u16*)(ws + 22 * MB);
  u16* vtb = (u16*)(ws + 30 * MB);
  u16* h2 = vtb;
  u16* W1T = (u16*)(ws + 38 * MB);
  u16* W2T = W1T;
  u16* pwo = (u16*)(ws + 46 * MB);
  u16* yb = (u16*)(ws + 46 * MB);
  u16* pf2 = (u16*)(ws + 0);

  // 1. LN1: x -> h (bf16)
  ln_kernel<<<4096, 256, 0, stream>>>(x, g1, be1, h);
  // 2. QKV weight transposes, one launch (per-head [1024][64] -> [64][1024])
  transpose_qkv3<<<dim3(2, 32, 48), 256, 0, stream>>>(Wq, Wk, Wv, BtQKV);
  // 3. QKV projection: [4096][1024] x [3072][1024]^T, scatter epilogue (q pre-scaled)
  gemm8p<0><<<dim3(12, 16), 512, 0, stream>>>(h, BtQKV, 4096, 3072, 1024, 1024,
                                              (void*)qb, kb, vtb, nullptr);
  // 4. causal attention -> o (bf16 [B][T][D]); 16 adjacent-paired blocks x 32 bh
  attn_kernel<<<dim3(16, 32), 512, 0, stream>>>(qb, kb, vtb, o);
  // 5. Wo transpose
  transpose_f32_bf16<<<dim3(32, 32, 1), 256, 0, stream>>>(Wo, WoT, 1024, 1024, 0, 0);
  // 6. Wo split-K=4: bf16 partials = o@Wo -> pwo
  gemm8p<4><<<dim3(4, 16, 4), 512, 0, stream>>>(o, WoT, 4096, 1024, 1024, 256,
                                                (void*)pwo, nullptr, nullptr, nullptr);
  // 7. fused: out = x + bo + sum(pwo); h2 = ln2(out)
  combine_ln<<<4096, 256, 0, stream>>>(x, pwo, bo, g2, be2, out, h2);
  // 8. W1 transpose [1024][4096] -> [4096][1024]
  transpose_f32_bf16<<<dim3(128, 32, 1), 256, 0, stream>>>(W1, W1T, 1024, 4096, 0, 0);
  // 9. FFN1: y = relu(h2@W1 + b1) (bf16)
  gemm8p<2><<<dim3(16, 16), 512, 0, stream>>>(h2, W1T, 4096, 4096, 1024, 1024,
                                              (void*)yb, nullptr, nullptr, b1);
  // 10. W2 transpose [4096][1024] -> [1024][4096]
  transpose_f32_bf16<<<dim3(32, 128, 1), 256, 0, stream>>>(W2, W2T, 4096, 1024, 0, 0);
  // 11. FFN2 split-K=4: bf16 partials = y@W2 -> pf2
  gemm8p<4><<<dim3(4, 16, 4), 512, 0, stream>>>(yb, W2T, 4096, 1024, 4096, 1024,
                                                (void*)pf2, nullptr, nullptr, nullptr);
  // 12. out = x1 + b2 + sum(pf2)
  combine4<<<4096, 256, 0, stream>>>(out, out, pf2, b2);
}

// Round 11
// 209.532 us; speedup vs baseline: 1.1184x; 1.0895x over previous
//
#include <hip/hip_runtime.h>
#include <stdint.h>

typedef unsigned short u16;
typedef __attribute__((ext_vector_type(8))) short bf16x8;
typedef __attribute__((ext_vector_type(4))) float f32x4;
typedef __attribute__((ext_vector_type(4))) unsigned int u32x4;
typedef __attribute__((ext_vector_type(2))) unsigned int u32x2;
typedef __attribute__((ext_vector_type(4))) unsigned short u16x4;

#define MFMA16(a, b, c) __builtin_amdgcn_mfma_f32_16x16x32_bf16(a, b, c, 0, 0, 0)
#define VMCNT(N) asm volatile("s_waitcnt vmcnt(" #N ")" ::: "memory")
#define LGKM0() asm volatile("s_waitcnt lgkmcnt(0)" ::: "memory")

__device__ __forceinline__ u16 f2bf(float f) {
  union { float f; uint32_t u; } v; v.f = f;
  uint32_t r = v.u + 0x7FFFu + ((v.u >> 16) & 1u);
  return (u16)(r >> 16);
}

__device__ __forceinline__ float bf2f(u16 u) {
  union { uint32_t u; float f; } v; v.u = ((uint32_t)u) << 16;
  return v.f;
}

__device__ __forceinline__ uint32_t cvt_pk_bf16(float a, float b) {
  uint32_t r;
  asm("v_cvt_pk_bf16_f32 %0, %1, %2" : "=v"(r) : "v"(a), "v"(b));
  return r;
}

// async global->LDS, 16B per lane. LDS dest is wave-uniform base + lane*16.
__device__ __forceinline__ void gload_lds16(const u16* g, u16* l) {
  __builtin_amdgcn_global_load_lds((const __attribute__((address_space(1))) void*)(g),
                                   (__attribute__((address_space(3))) void*)(l), 16, 0, 0);
}

// ------------- prep mega-kernel: LN1 + all weight transposes, one launch -------------
// blocks 0..4095       : LN1 row b (x fp32 -> h bf16)
// blocks 4096..7167    : Wq/Wk/Wv per-head [1024][64] -> BtQKV [64][1024] bf16
// blocks 7168..8191    : Wo   [1024][1024] -> WoT
// blocks 8192..12287   : W1   [1024][4096] -> W1T [4096][1024]
// blocks 12288..16383  : W2   [4096][1024] -> W2T [1024][4096]
__global__ __launch_bounds__(256) void prep_kernel(
    const float* __restrict__ x, const float* __restrict__ g1,
    const float* __restrict__ be1, u16* __restrict__ h,
    const float* __restrict__ Wq, const float* __restrict__ Wk,
    const float* __restrict__ Wv, u16* __restrict__ BtQKV,
    const float* __restrict__ Wo, u16* __restrict__ WoT,
    const float* __restrict__ W1, u16* __restrict__ W1T,
    const float* __restrict__ W2, u16* __restrict__ W2T) {
  __shared__ float tile[32][33];
  __shared__ float red[8];
  int bid = blockIdx.x, tid = threadIdx.x;
  if (bid < 4096) {
    int row = bid;
    float4 v = ((const float4*)(x + (size_t)row * 1024))[tid];
    float s = v.x + v.y + v.z + v.w;
    float ss = v.x * v.x + v.y * v.y + v.z * v.z + v.w * v.w;
#pragma unroll
    for (int m = 1; m < 64; m <<= 1) { s += __shfl_xor(s, m); ss += __shfl_xor(ss, m); }
    int wave = tid >> 6, lane = tid & 63;
    if (lane == 0) { red[wave] = s; red[4 + wave] = ss; }
    __syncthreads();
    s = red[0] + red[1] + red[2] + red[3];
    ss = red[4] + red[5] + red[6] + red[7];
    float mean = s * (1.0f / 1024.0f);
    float var = ss * (1.0f / 1024.0f) - mean * mean;
    float rstd = rsqrtf(var + 1e-5f);
    float4 gv = ((const float4*)g1)[tid];
    float4 bv = ((const float4*)be1)[tid];
    u16x4 o;
    o.x = f2bf((v.x - mean) * rstd * gv.x + bv.x);
    o.y = f2bf((v.y - mean) * rstd * gv.y + bv.y);
    o.z = f2bf((v.z - mean) * rstd * gv.z + bv.z);
    o.w = f2bf((v.w - mean) * rstd * gv.w + bv.w);
    *(u16x4*)(h + (size_t)row * 1024 + tid * 4) = o;
    return;
  }
  const float* I;
  u16* O;
  int K, N, n0, k0;
  if (bid < 7168) {
    int idx = bid - 4096;           // grid (2,32,48): idx = bz*64 + by*2 + bx
    int bz = idx >> 6, by = (idx >> 1) & 31, bx = idx & 1;
    int ww = bz >> 4, head = bz & 15;
    I = ((ww == 0) ? Wq : (ww == 1) ? Wk : Wv) + (size_t)head * 65536;
    O = BtQKV + (size_t)ww * 1048576 + (size_t)head * 65536;
    K = 1024; N = 64; n0 = bx * 32; k0 = by * 32;
  } else if (bid < 8192) {
    int idx = bid - 7168;
    I = Wo; O = WoT; K = 1024; N = 1024;
    n0 = (idx & 31) * 32; k0 = (idx >> 5) * 32;
  } else if (bid < 12288) {
    int idx = bid - 8192;
    I = W1; O = W1T; K = 1024; N = 4096;
    n0 = (idx & 127) * 32; k0 = (idx >> 7) * 32;
  } else {
    int idx = bid - 12288;
    I = W2; O = W2T; K = 4096; N = 1024;
    n0 = (idx & 31) * 32; k0 = (idx >> 5) * 32;
  }
  int tx = tid & 31, ty = tid >> 5;
#pragma unroll
  for (int i = 0; i < 4; i++)
    tile[ty + i * 8][tx] = I[(size_t)(k0 + ty + i * 8) * N + n0 + tx];
  __syncthreads();
#pragma unroll
  for (int i = 0; i < 4; i++)
    O[(size_t)(n0 + ty + i * 8) * K + k0 + tx] = f2bf(tile[tx][ty + i * 8]);
}

// ---- fused Wo-combine + LN2: out = x + bo + sum(p[z]); h2 = ln2(out) ----
__global__ __launch_bounds__(256) void combine_ln(const float* __restrict__ x,
                                                  const u16* __restrict__ p,
                                                  const float* __restrict__ bo,
                                                  const float* __restrict__ g,
                                                  const float* __restrict__ beta,
                                                  float* __restrict__ out,
                                                  u16* __restrict__ h2) {
  int row = blockIdx.x;
  int tid = threadIdx.x;
  size_t i = (size_t)row * 1024 + tid * 4;
  float4 v = *(const float4*)(x + i);
  float4 bb = *(const float4*)(bo + tid * 4);
  v.x += bb.x; v.y += bb.y; v.z += bb.z; v.w += bb.w;
#pragma unroll
  for (int z = 0; z < 4; z++) {
    u16x4 pv = *(const u16x4*)(p + (size_t)z * 4096 * 1024 + i);
    v.x += bf2f(pv.x); v.y += bf2f(pv.y); v.z += bf2f(pv.z); v.w += bf2f(pv.w);
  }
  *(float4*)(out + i) = v;
  float s = v.x + v.y + v.z + v.w;
  float ss = v.x * v.x + v.y * v.y + v.z * v.z + v.w * v.w;
#pragma unroll
  for (int m = 1; m < 64; m <<= 1) { s += __shfl_xor(s, m); ss += __shfl_xor(ss, m); }
  __shared__ float red[8];
  int wave = tid >> 6, lane = tid & 63;
  if (lane == 0) { red[wave] = s; red[4 + wave] = ss; }
  __syncthreads();
  s = red[0] + red[1] + red[2] + red[3];
  ss = red[4] + red[5] + red[6] + red[7];
  float mean = s * (1.0f / 1024.0f);
  float var = ss * (1.0f / 1024.0f) - mean * mean;
  float rstd = rsqrtf(var + 1e-5f);
  float4 gv = ((const float4*)g)[tid];
  float4 bv = ((const float4*)beta)[tid];
  u16x4 o;
  o.x = f2bf((v.x - mean) * rstd * gv.x + bv.x);
  o.y = f2bf((v.y - mean) * rstd * gv.y + bv.y);
  o.z = f2bf((v.z - mean) * rstd * gv.z + bv.z);
  o.w = f2bf((v.w - mean) * rstd * gv.w + bv.w);
  *(u16x4*)(h2 + i) = o;
}

// ---------------- 256x256 8-phase GEMM: C[M][N] = A[M][K] * Bt[N][K]^T ----------------
// m201-conformant schedule (see round 8). EP 0: QKV scatter; EP 2: relu+bias bf16;
// EP 4: bf16 split-K partial.
template <int EP>
__global__ __launch_bounds__(512, 2) void gemm8p(const u16* __restrict__ A,
                                                 const u16* __restrict__ Bt,
                                                 int M, int N, int K, int KS,
                                                 void* __restrict__ out0,
                                                 u16* __restrict__ out1,
                                                 u16* __restrict__ out2,
                                                 const float* __restrict__ bias) {
  __shared__ __align__(16) u16 lds[65536];  // A at 0, B at 32768 (u16 units)
  const int tid = threadIdx.x;
  const int lane = tid & 63, wave = tid >> 6;
  const int lo = lane & 15, hi = lane >> 4;
  const int wm = wave >> 2, wn = wave & 3;
  // XCD swizzle
  int gx = gridDim.x;
  int lin = blockIdx.y * gx + blockIdx.x;
  int nwg = gx * gridDim.y;
  int cpx = nwg >> 3;
  int swz = (lin & 7) * cpx + (lin >> 3);
  int bm0 = (swz / gx) * 256, bn0 = (swz % gx) * 256;
  int kbeg = blockIdx.z * KS;
  int T = KS >> 6;

  int rs_ = tid >> 3, ss_ = (tid & 7) ^ (rs_ & 7);
  const u16* srcA = A + (size_t)(bm0 + rs_) * K + kbeg + ss_ * 8;
  const u16* srcB = Bt + (size_t)(bn0 + rs_) * K + kbeg + ss_ * 8;
  const size_t i1 = (size_t)64 * K;
  const size_t h1 = (size_t)128 * K;
  const int dst0 = wave * 512;
  const int dst1 = 4096 + wave * 512;

  const int rpA = wm * 16 + lo;
  const int rpB = wn * 16 + lo;
  const int sp0 = (hi ^ (lo & 7)) * 8;

  f32x4 acc[8][4] = {};
  bf16x8 a[4][2], b0[2][2], b1[2][2];

  auto stageA = [&](int buf, int h, int koff) {
    const u16* s = srcA + koff + (h ? h1 : 0);
    u16* d = lds + (buf * 2 + h) * 8192;
    gload_lds16(s, d + dst0);
    gload_lds16(s + i1, d + dst1);
  };
  auto stageB = [&](int buf, int h, int koff) {
    const u16* s = srcB + koff + (h ? h1 : 0);
    u16* d = lds + 32768 + (buf * 2 + h) * 8192;
    gload_lds16(s, d + dst0);
    gload_lds16(s + i1, d + dst1);
  };
  auto loadA = [&](int buf, int h) {
    const u16* base = lds + (buf * 2 + h) * 8192 + rpA * 64;
#pragma unroll
    for (int m = 0; m < 4; m++) {
      a[m][0] = *(const bf16x8*)(base + m * 2048 + sp0);
      a[m][1] = *(const bf16x8*)(base + m * 2048 + (sp0 ^ 32));
    }
  };
  auto loadB = [&](bf16x8 (&bb)[2][2], int buf, int g) {
    const u16* base = lds + 32768 + (buf * 2 + g) * 8192 + rpB * 64;
#pragma unroll
    for (int n = 0; n < 2; n++) {
      bb[n][0] = *(const bf16x8*)(base + n * 4096 + sp0);
      bb[n][1] = *(const bf16x8*)(base + n * 4096 + (sp0 ^ 32));
    }
  };
  auto mmac = [&](int mh, int np, bf16x8 (&bb)[2][2]) {
    __builtin_amdgcn_s_setprio(1);
#pragma unroll
    for (int m = 0; m < 4; m++)
#pragma unroll
      for (int n = 0; n < 2; n++) {
        acc[mh + m][np + n] = MFMA16(a[m][0], bb[n][0], acc[mh + m][np + n]);
        acc[mh + m][np + n] = MFMA16(a[m][1], bb[n][1], acc[mh + m][np + n]);
      }
    __builtin_amdgcn_s_setprio(0);
  };

  stageA(0, 0, 0); stageB(0, 0, 0); stageB(0, 1, 0); stageA(0, 1, 0);
  VMCNT(4);
  __builtin_amdgcn_s_barrier();

  for (int t = 0; t < T; ++t) {
    int cur = t & 1, nxt = cur ^ 1;
    bool more = (t + 1 < T);
    int koff = (t + 1) * 64;
    // P1
    loadA(cur, 0); loadB(b0, cur, 0);
    if (more) stageA(nxt, 0, koff);
    __builtin_amdgcn_s_barrier();
    LGKM0();
    __builtin_amdgcn_sched_barrier(0);
    mmac(0, 0, b0);
    __builtin_amdgcn_s_barrier();
    // P2
    loadB(b1, cur, 1);
    if (more) { stageB(nxt, 0, koff); VMCNT(6); } else { VMCNT(2); }
    __builtin_amdgcn_s_barrier();
    LGKM0();
    __builtin_amdgcn_sched_barrier(0);
    mmac(0, 2, b1);
    __builtin_amdgcn_s_barrier();
    // P3
    loadA(cur, 1);
    if (more) { stageB(nxt, 1, koff); VMCNT(6); } else { VMCNT(0); }
    __builtin_amdgcn_s_barrier();
    LGKM0();
    __builtin_amdgcn_sched_barrier(0);
    mmac(4, 0, b0);
    __builtin_amdgcn_s_barrier();
    // P4
    if (more) { stageA(nxt, 1, koff); VMCNT(4); }
    __builtin_amdgcn_s_barrier();
    mmac(4, 2, b1);
    __builtin_amdgcn_s_barrier();
  }

  const int sec = (EP == 0) ? (bn0 >> 10) : 0;
#pragma unroll
  for (int mt = 0; mt < 8; mt++) {
    int gr0 = bm0 + (mt >> 2) * 128 + (mt & 3) * 32 + wm * 16 + hi * 4;
#pragma unroll
    for (int nt = 0; nt < 4; nt++) {
      int gc = bn0 + (nt >> 1) * 128 + (nt & 1) * 64 + wn * 16 + lo;
      if constexpr (EP == 0) {
        int b_ = gr0 >> 11, t_ = gr0 & 2047;
        int nn = gc & 1023, h_ = nn >> 6, e_ = nn & 63;
        size_t bh = (size_t)(b_ * 16 + h_);
        if (sec == 2) {  // vT: 4 consecutive t per thread -> one 8B store
          u32x2 w;
          w.x = cvt_pk_bf16(acc[mt][nt][0], acc[mt][nt][1]);
          w.y = cvt_pk_bf16(acc[mt][nt][2], acc[mt][nt][3]);
          *(u32x2*)(out2 + (bh * 64 + e_) * 2048 + t_) = w;
        } else {
          float sc = (sec == 0) ? 0.0450842200f : 1.0f;  // q pre-scale D^-0.5*log2e
          u16* dst = (sec == 0) ? (u16*)out0 : out1;
#pragma unroll
          for (int j = 0; j < 4; j++)
            dst[(bh * 2048 + t_ + j) * 64 + e_] = f2bf(acc[mt][nt][j] * sc);
        }
      } else {
#pragma unroll
        for (int j = 0; j < 4; j++) {
          int gr = gr0 + j;
          float val = acc[mt][nt][j];
          if constexpr (EP == 2) {
            float v = val + bias[gc];
            ((u16*)out0)[(size_t)gr * N + gc] = f2bf(fmaxf(v, 0.0f));
          } else if constexpr (EP == 4) {
            ((u16*)out0)[(size_t)blockIdx.z * M * N + (size_t)gr * N + gc] = f2bf(val);
          }
        }
      }
    }
  }
}

// -------- split-K=4 combine: out = res + bias + sum(p[z]) (p bf16, 4096x1024) --------
__global__ __launch_bounds__(256) void combine4(float* __restrict__ out,
                                                const float* __restrict__ res,
                                                const u16* __restrict__ p,
                                                const float* __restrict__ bias) {
  size_t i = ((size_t)blockIdx.x * 256 + threadIdx.x) * 4;
  float4 r = *(const float4*)(res + i);
  float4 bb = *(const float4*)(bias + (i & 1023));
  float a0 = r.x + bb.x, a1 = r.y + bb.y, a2 = r.z + bb.z, a3 = r.w + bb.w;
#pragma unroll
  for (int z = 0; z < 4; z++) {
    u16x4 v = *(const u16x4*)(p + (size_t)z * 4096 * 1024 + i);
    a0 += bf2f(v.x); a1 += bf2f(v.y); a2 += bf2f(v.z); a3 += bf2f(v.w);
  }
  float4 o4 = {a0, a1, a2, a3};
  *(float4*)(out + i) = o4;
}

// ------------------------- causal flash attention (paired Q-tiles) -------------------------
// r8 structure (measured best). Block i of 16 handles Q-tiles (31-i) [waves 0-3] and
// (i) [waves 4-7] sharing one double-buffered K/V staging pipeline -> every block does
// exactly 33 active tile-computes; durations 17..32 pack well under 2-deep residency.
__global__ __launch_bounds__(512, 4) void attn_kernel(const u16* __restrict__ q,
                                                      const u16* __restrict__ k,
                                                      const u16* __restrict__ vt,
                                                      u16* __restrict__ o) {
  __shared__ __align__(16) u16 Ks[2][64 * 64];
  __shared__ __align__(16) u16 Vs[2][64 * 64];
  __shared__ __align__(16) u16 Ps[8][16 * 72];
  int bh = blockIdx.y;
  int pi = blockIdx.x;  // 0..15
  int tid = threadIdx.x, lane = tid & 63, wave = tid >> 6;
  int lo = lane & 15, hi = lane >> 4;
  int grp = wave >> 2;                      // 0: long tile, 1: short tile
  int qblk_w = grp ? pi : (31 - pi);
  int qb0 = qblk_w * 64;
  int nkb = 32 - pi;                        // loop length = long tile's KV count
  const u16* qbase = q + (size_t)bh * 2048 * 64;
  const u16* kbase = k + (size_t)bh * 2048 * 64;
  const u16* vbase = vt + (size_t)bh * 64 * 2048;

  // staging geometry: 512 threads x 16B = one 64x64 bf16 tile per matrix
  int srow = tid >> 3;
  int ssl = (tid & 7) ^ (srow & 7);         // both-sides XOR swizzle (pre-swizzled src)
  int kOff = srow * 64 + ssl * 8;
  int vOff = srow * 2048 + ssl * 8;

  int qrow = qb0 + (wave & 3) * 16 + lo;    // this lane's q-row (B-frag: n = lane&15)
  bf16x8 qf0 = *(const bf16x8*)(qbase + (size_t)qrow * 64 + hi * 8);
  bf16x8 qf1 = *(const bf16x8*)(qbase + (size_t)qrow * 64 + 32 + hi * 8);

  float l_r = 0.0f;
  f32x4 of[4] = {};
  u16* Pw = Ps[wave];

  auto stage = [&](int b, int kb) {
    gload_lds16(kbase + (size_t)kb * 4096 + kOff, Ks[b] + wave * 512);
    gload_lds16(vbase + kb * 64 + vOff, Vs[b] + wave * 512);
  };

  stage(0, 0);
  __syncthreads();  // drains vmcnt

  for (int kb = 0; kb < nkb; kb++) {
    int cur = kb & 1;
    if (kb + 1 < nkb) stage(cur ^ 1, kb + 1);  // async prefetch of next tile
    if (kb <= qblk_w) {
      const u16* Kb = Ks[cur];
      const u16* Vb = Vs[cur];
      // S^T = K Q^T : D[key][q], key = nt*16 + hi*4 + jj, q = lo
      f32x4 s4[4] = {};
#pragma unroll
      for (int nt = 0; nt < 4; nt++) {
        int r = nt * 16 + lo, rw = r & 7;
        bf16x8 kf0 = *(const bf16x8*)(Kb + r * 64 + ((hi ^ rw) << 3));
        bf16x8 kf1 = *(const bf16x8*)(Kb + r * 64 + (((hi + 4) ^ rw) << 3));
        s4[nt] = MFMA16(kf0, qf0, s4[nt]);
        s4[nt] = MFMA16(kf1, qf1, s4[nt]);
      }
      // exp2 (fixed max) + row-sum; P -> LDS [q][key] packed 4-wide
      float rs = 0.0f;
      bool diag = (kb == qblk_w);
#pragma unroll
      for (int nt = 0; nt < 4; nt++) {
        float e0, e1, e2, e3;
        if (diag) {
          int key = kb * 64 + nt * 16 + hi * 4;
          e0 = (key     > qrow) ? 0.0f : __builtin_amdgcn_exp2f(s4[nt][0]);
          e1 = (key + 1 > qrow) ? 0.0f : __builtin_amdgcn_exp2f(s4[nt][1]);
          e2 = (key + 2 > qrow) ? 0.0f : __builtin_amdgcn_exp2f(s4[nt][2]);
          e3 = (key + 3 > qrow) ? 0.0f : __builtin_amdgcn_exp2f(s4[nt][3]);
        } else {
          e0 = __builtin_amdgcn_exp2f(s4[nt][0]);
          e1 = __builtin_amdgcn_exp2f(s4[nt][1]);
          e2 = __builtin_amdgcn_exp2f(s4[nt][2]);
          e3 = __builtin_amdgcn_exp2f(s4[nt][3]);
        }
        rs += (e0 + e1) + (e2 + e3);
        u32x2 w;
        w.x = cvt_pk_bf16(e0, e1);
        w.y = cvt_pk_bf16(e2, e3);
        *(u32x2*)(Pw + lo * 72 + nt * 16 + hi * 4) = w;
      }
      rs += __shfl_xor(rs, 16);
      rs += __shfl_xor(rs, 32);
      l_r += rs;
      // O^T += Vt P^T : D[d][q], d = et*16 + hi*4 + jj, q = lo
      bf16x8 pb0 = *(const bf16x8*)(Pw + lo * 72 + hi * 8);
      bf16x8 pb1 = *(const bf16x8*)(Pw + lo * 72 + 32 + hi * 8);
#pragma unroll
      for (int et = 0; et < 4; et++) {
        int e = et * 16 + lo, ew = e & 7;
        bf16x8 v0 = *(const bf16x8*)(Vb + e * 64 + ((hi ^ ew) << 3));
        bf16x8 v1 = *(const bf16x8*)(Vb + e * 64 + (((hi + 4) ^ ew) << 3));
        of[et] = MFMA16(v0, pb0, of[et]);
        of[et] = MFMA16(v1, pb1, of[et]);
      }
    }
    __syncthreads();  // next tile staged; all waves done with cur
  }
  // write O (q-row = lo, d contiguous in jj -> 8B packed stores)
  int hh = bh & 15, bb = bh >> 4;
  float inv = 1.0f / l_r;
  size_t obase = ((size_t)(bb * 2048 + qrow)) * 1024 + hh * 64 + hi * 4;
#pragma unroll
  for (int et = 0; et < 4; et++) {
    u32x2 w;
    w.x = cvt_pk_bf16(of[et][0] * inv, of[et][1] * inv);
    w.y = cvt_pk_bf16(of[et][2] * inv, of[et][3] * inv);
    *(u32x2*)(o + obase + et * 16) = w;
  }
}

extern "C" void kernel_launch(void* const* d_in, const int* in_sizes, int n_in,
                              void* d_out, int out_size, void* d_ws, size_t ws_size,
                              hipStream_t stream) {
  const float* x = (const float*)d_in[0];
  const float* Wq = (const float*)d_in[1];
  const float* Wk = (const float*)d_in[2];
  const float* Wv = (const float*)d_in[3];
  const float* Wo = (const float*)d_in[4];
  const float* bo = (const float*)d_in[5];
  const float* W1 = (const float*)d_in[6];
  const float* b1 = (const float*)d_in[7];
  const float* W2 = (const float*)d_in[8];
  const float* b2 = (const float*)d_in[9];
  const float* g1 = (const float*)d_in[10];
  const float* be1 = (const float*)d_in[11];
  const float* g2 = (const float*)d_in[12];
  const float* be2 = (const float*)d_in[13];
  float* out = (float*)d_out;
  char* ws = (char*)d_ws;
  const size_t MB = 1024ull * 1024ull;

  // workspace map (78MB peak), all transposes materialized up front:
  //  0- 8 : h (ln1) -> o (attn out) -> pf2[0]
  //  8-14 : BtQKV               -> h2 (after Wo gemm) / pf2[1]
  // 14-16 : WoT                 -> (pf2[1] tail)
  // 16-24 : W1T                 -> pf2[2]
  // 24-32 : (free)              -> pf2[3]
  // 32-40 : qb   -> pwo[0] -> yb[0..]
  // 40-48 : kb   -> pwo[1] ...
  // 48-56 : vtb  -> pwo[2] ...   (pwo 32MB = 32-64; yb 32MB = 32-64 after combine_ln)
  // 56-64 :      -> pwo[3] ...
  // 64-72 : W2T (persists until FFN2)
  u16* h = (u16*)(ws + 0);
  u16* o = h;
  u16* BtQKV = (u16*)(ws + 8 * MB);
  u16* WoT = (u16*)(ws + 14 * MB);
  u16* W1T = (u16*)(ws + 16 * MB);
  u16* W2T = (u16*)(ws + 64 * MB);
  u16* qb = (u16*)(ws + 32 * MB);
  u16* kb = (u16*)(ws + 40 * MB);
  u16* vtb = (u16*)(ws + 48 * MB);
  u16* h2 = (u16*)(ws + 8 * MB);
  u16* pwo = (u16*)(ws + 32 * MB);
  u16* yb = (u16*)(ws + 32 * MB);
  u16* pf2 = (u16*)(ws + 0);

  // 1. prep: LN1 + all weight transposes (one launch)
  prep_kernel<<<16384, 256, 0, stream>>>(x, g1, be1, h, Wq, Wk, Wv, BtQKV,
                                         Wo, WoT, W1, W1T, W2, W2T);
  // 2. QKV projection: [4096][1024] x [3072][1024]^T, scatter epilogue (q pre-scaled)
  gemm8p<0><<<dim3(12, 16), 512, 0, stream>>>(h, BtQKV, 4096, 3072, 1024, 1024,
                                              (void*)qb, kb, vtb, nullptr);
  // 3. causal attention -> o (bf16 [B][T][D]); 16 mirrored-paired blocks x 32 bh
  attn_kernel<<<dim3(16, 32), 512, 0, stream>>>(qb, kb, vtb, o);
  // 4. Wo split-K=4: bf16 partials = o@Wo -> pwo
  gemm8p<4><<<dim3(4, 16, 4), 512, 0, stream>>>(o, WoT, 4096, 1024, 1024, 256,
                                                (void*)pwo, nullptr, nullptr, nullptr);
  // 5. fused: out = x + bo + sum(pwo); h2 = ln2(out)
  combine_ln<<<4096, 256, 0, stream>>>(x, pwo, bo, g2, be2, out, h2);
  // 6. FFN1: y = relu(h2@W1 + b1) (bf16)
  gemm8p<2><<<dim3(16, 16), 512, 0, stream>>>(h2, W1T, 4096, 4096, 1024, 1024,
                                              (void*)yb, nullptr, nullptr, b1);
  // 7. FFN2 split-K=4: bf16 partials = y@W2 -> pf2
  gemm8p<4><<<dim3(4, 16, 4), 512, 0, stream>>>(yb, W2T, 4096, 1024, 4096, 1024,
                                                (void*)pf2, nullptr, nullptr, nullptr);
  // 8. out = x1 + b2 + sum(pf2)
  combine4<<<4096, 256, 0, stream>>>(out, out, pf2, b2);
}

// Round 12
// 207.763 us; speedup vs baseline: 1.1279x; 1.0085x over previous
//
#include <hip/hip_runtime.h>
#include <stdint.h>

typedef unsigned short u16;
typedef __attribute__((ext_vector_type(8))) short bf16x8;
typedef __attribute__((ext_vector_type(4))) float f32x4;
typedef __attribute__((ext_vector_type(4))) unsigned int u32x4;
typedef __attribute__((ext_vector_type(2))) unsigned int u32x2;
typedef __attribute__((ext_vector_type(4))) unsigned short u16x4;

#define MFMA16(a, b, c) __builtin_amdgcn_mfma_f32_16x16x32_bf16(a, b, c, 0, 0, 0)
#define VMCNT(N) asm volatile("s_waitcnt vmcnt(" #N ")" ::: "memory")
#define LGKM0() asm volatile("s_waitcnt lgkmcnt(0)" ::: "memory")

__device__ __forceinline__ u16 f2bf(float f) {
  union { float f; uint32_t u; } v; v.f = f;
  uint32_t r = v.u + 0x7FFFu + ((v.u >> 16) & 1u);
  return (u16)(r >> 16);
}

__device__ __forceinline__ float bf2f(u16 u) {
  union { uint32_t u; float f; } v; v.u = ((uint32_t)u) << 16;
  return v.f;
}

__device__ __forceinline__ uint32_t cvt_pk_bf16(float a, float b) {
  uint32_t r;
  asm("v_cvt_pk_bf16_f32 %0, %1, %2" : "=v"(r) : "v"(a), "v"(b));
  return r;
}

// async global->LDS, 16B per lane. LDS dest is wave-uniform base + lane*16.
__device__ __forceinline__ void gload_lds16(const u16* g, u16* l) {
  __builtin_amdgcn_global_load_lds((const __attribute__((address_space(1))) void*)(g),
                                   (__attribute__((address_space(3))) void*)(l), 16, 0, 0);
}

// ------------- prep mega-kernel: LN1 + all weight transposes, one launch -------------
// blocks 0..4095       : LN1 row b (x fp32 -> h bf16)
// blocks 4096..7167    : Wq/Wk/Wv per-head [1024][64] -> BtQKV [64][1024] bf16
// blocks 7168..8191    : Wo   [1024][1024] -> WoT
// blocks 8192..12287   : W1   [1024][4096] -> W1T [4096][1024]
// blocks 12288..16383  : W2   [4096][1024] -> W2T [1024][4096]
__global__ __launch_bounds__(256) void prep_kernel(
    const float* __restrict__ x, const float* __restrict__ g1,
    const float* __restrict__ be1, u16* __restrict__ h,
    const float* __restrict__ Wq, const float* __restrict__ Wk,
    const float* __restrict__ Wv, u16* __restrict__ BtQKV,
    const float* __restrict__ Wo, u16* __restrict__ WoT,
    const float* __restrict__ W1, u16* __restrict__ W1T,
    const float* __restrict__ W2, u16* __restrict__ W2T) {
  __shared__ float tile[32][33];
  __shared__ float red[8];
  int bid = blockIdx.x, tid = threadIdx.x;
  if (bid < 4096) {
    int row = bid;
    float4 v = ((const float4*)(x + (size_t)row * 1024))[tid];
    float s = v.x + v.y + v.z + v.w;
    float ss = v.x * v.x + v.y * v.y + v.z * v.z + v.w * v.w;
#pragma unroll
    for (int m = 1; m < 64; m <<= 1) { s += __shfl_xor(s, m); ss += __shfl_xor(ss, m); }
    int wave = tid >> 6, lane = tid & 63;
    if (lane == 0) { red[wave] = s; red[4 + wave] = ss; }
    __syncthreads();
    s = red[0] + red[1] + red[2] + red[3];
    ss = red[4] + red[5] + red[6] + red[7];
    float mean = s * (1.0f / 1024.0f);
    float var = ss * (1.0f / 1024.0f) - mean * mean;
    float rstd = rsqrtf(var + 1e-5f);
    float4 gv = ((const float4*)g1)[tid];
    float4 bv = ((const float4*)be1)[tid];
    u16x4 o;
    o.x = f2bf((v.x - mean) * rstd * gv.x + bv.x);
    o.y = f2bf((v.y - mean) * rstd * gv.y + bv.y);
    o.z = f2bf((v.z - mean) * rstd * gv.z + bv.z);
    o.w = f2bf((v.w - mean) * rstd * gv.w + bv.w);
    *(u16x4*)(h + (size_t)row * 1024 + tid * 4) = o;
    return;
  }
  const float* I;
  u16* O;
  int K, N, n0, k0;
  if (bid < 7168) {
    int idx = bid - 4096;
    int bz = idx >> 6, by = (idx >> 1) & 31, bx = idx & 1;
    int ww = bz >> 4, head = bz & 15;
    I = ((ww == 0) ? Wq : (ww == 1) ? Wk : Wv) + (size_t)head * 65536;
    O = BtQKV + (size_t)ww * 1048576 + (size_t)head * 65536;
    K = 1024; N = 64; n0 = bx * 32; k0 = by * 32;
  } else if (bid < 8192) {
    int idx = bid - 7168;
    I = Wo; O = WoT; K = 1024; N = 1024;
    n0 = (idx & 31) * 32; k0 = (idx >> 5) * 32;
  } else if (bid < 12288) {
    int idx = bid - 8192;
    I = W1; O = W1T; K = 1024; N = 4096;
    n0 = (idx & 127) * 32; k0 = (idx >> 7) * 32;
  } else {
    int idx = bid - 12288;
    I = W2; O = W2T; K = 4096; N = 1024;
    n0 = (idx & 31) * 32; k0 = (idx >> 5) * 32;
  }
  int tx = tid & 31, ty = tid >> 5;
#pragma unroll
  for (int i = 0; i < 4; i++)
    tile[ty + i * 8][tx] = I[(size_t)(k0 + ty + i * 8) * N + n0 + tx];
  __syncthreads();
#pragma unroll
  for (int i = 0; i < 4; i++)
    O[(size_t)(n0 + ty + i * 8) * K + k0 + tx] = f2bf(tile[tx][ty + i * 8]);
}

// ---------------- LayerNorm: fp32 [rows][1024] -> bf16 [rows][1024] ----------------
__global__ __launch_bounds__(256) void ln_kernel(const float* __restrict__ x,
                                                 const float* __restrict__ g,
                                                 const float* __restrict__ beta,
                                                 u16* __restrict__ out) {
  int row = blockIdx.x;
  int tid = threadIdx.x;
  float4 v = ((const float4*)(x + (size_t)row * 1024))[tid];
  float s = v.x + v.y + v.z + v.w;
  float ss = v.x * v.x + v.y * v.y + v.z * v.z + v.w * v.w;
#pragma unroll
  for (int m = 1; m < 64; m <<= 1) { s += __shfl_xor(s, m); ss += __shfl_xor(ss, m); }
  __shared__ float red[8];
  int wave = tid >> 6, lane = tid & 63;
  if (lane == 0) { red[wave] = s; red[4 + wave] = ss; }
  __syncthreads();
  s = red[0] + red[1] + red[2] + red[3];
  ss = red[4] + red[5] + red[6] + red[7];
  float mean = s * (1.0f / 1024.0f);
  float var = ss * (1.0f / 1024.0f) - mean * mean;
  float rstd = rsqrtf(var + 1e-5f);
  float4 gv = ((const float4*)g)[tid];
  float4 bv = ((const float4*)beta)[tid];
  u16x4 o;
  o.x = f2bf((v.x - mean) * rstd * gv.x + bv.x);
  o.y = f2bf((v.y - mean) * rstd * gv.y + bv.y);
  o.z = f2bf((v.z - mean) * rstd * gv.z + bv.z);
  o.w = f2bf((v.w - mean) * rstd * gv.w + bv.w);
  *(u16x4*)(out + (size_t)row * 1024 + tid * 4) = o;
}

// ---------------- 256x256 8-phase GEMM: C[M][N] = A[M][K] * Bt[N][K]^T ----------------
// m201-conformant schedule. EP 0: QKV scatter; EP 2: relu+bias bf16 (FFN1).
template <int EP>
__global__ __launch_bounds__(512, 2) void gemm8p(const u16* __restrict__ A,
                                                 const u16* __restrict__ Bt,
                                                 int M, int N, int K, int KS,
                                                 void* __restrict__ out0,
                                                 u16* __restrict__ out1,
                                                 u16* __restrict__ out2,
                                                 const float* __restrict__ bias) {
  __shared__ __align__(16) u16 lds[65536];  // A at 0, B at 32768 (u16 units)
  const int tid = threadIdx.x;
  const int lane = tid & 63, wave = tid >> 6;
  const int lo = lane & 15, hi = lane >> 4;
  const int wm = wave >> 2, wn = wave & 3;
  // XCD swizzle
  int gx = gridDim.x;
  int lin = blockIdx.y * gx + blockIdx.x;
  int nwg = gx * gridDim.y;
  int cpx = nwg >> 3;
  int swz = (lin & 7) * cpx + (lin >> 3);
  int bm0 = (swz / gx) * 256, bn0 = (swz % gx) * 256;
  int kbeg = blockIdx.z * KS;
  int T = KS >> 6;

  int rs_ = tid >> 3, ss_ = (tid & 7) ^ (rs_ & 7);
  const u16* srcA = A + (size_t)(bm0 + rs_) * K + kbeg + ss_ * 8;
  const u16* srcB = Bt + (size_t)(bn0 + rs_) * K + kbeg + ss_ * 8;
  const size_t i1 = (size_t)64 * K;
  const size_t h1 = (size_t)128 * K;
  const int dst0 = wave * 512;
  const int dst1 = 4096 + wave * 512;

  const int rpA = wm * 16 + lo;
  const int rpB = wn * 16 + lo;
  const int sp0 = (hi ^ (lo & 7)) * 8;

  f32x4 acc[8][4] = {};
  bf16x8 a[4][2], b0[2][2], b1[2][2];

  auto stageA = [&](int buf, int h, int koff) {
    const u16* s = srcA + koff + (h ? h1 : 0);
    u16* d = lds + (buf * 2 + h) * 8192;
    gload_lds16(s, d + dst0);
    gload_lds16(s + i1, d + dst1);
  };
  auto stageB = [&](int buf, int h, int koff) {
    const u16* s = srcB + koff + (h ? h1 : 0);
    u16* d = lds + 32768 + (buf * 2 + h) * 8192;
    gload_lds16(s, d + dst0);
    gload_lds16(s + i1, d + dst1);
  };
  auto loadA = [&](int buf, int h) {
    const u16* base = lds + (buf * 2 + h) * 8192 + rpA * 64;
#pragma unroll
    for (int m = 0; m < 4; m++) {
      a[m][0] = *(const bf16x8*)(base + m * 2048 + sp0);
      a[m][1] = *(const bf16x8*)(base + m * 2048 + (sp0 ^ 32));
    }
  };
  auto loadB = [&](bf16x8 (&bb)[2][2], int buf, int g) {
    const u16* base = lds + 32768 + (buf * 2 + g) * 8192 + rpB * 64;
#pragma unroll
    for (int n = 0; n < 2; n++) {
      bb[n][0] = *(const bf16x8*)(base + n * 4096 + sp0);
      bb[n][1] = *(const bf16x8*)(base + n * 4096 + (sp0 ^ 32));
    }
  };
  auto mmac = [&](int mh, int np, bf16x8 (&bb)[2][2]) {
    __builtin_amdgcn_s_setprio(1);
#pragma unroll
    for (int m = 0; m < 4; m++)
#pragma unroll
      for (int n = 0; n < 2; n++) {
        acc[mh + m][np + n] = MFMA16(a[m][0], bb[n][0], acc[mh + m][np + n]);
        acc[mh + m][np + n] = MFMA16(a[m][1], bb[n][1], acc[mh + m][np + n]);
      }
    __builtin_amdgcn_s_setprio(0);
  };

  stageA(0, 0, 0); stageB(0, 0, 0); stageB(0, 1, 0); stageA(0, 1, 0);
  VMCNT(4);
  __builtin_amdgcn_s_barrier();

  for (int t = 0; t < T; ++t) {
    int cur = t & 1, nxt = cur ^ 1;
    bool more = (t + 1 < T);
    int koff = (t + 1) * 64;
    // P1
    loadA(cur, 0); loadB(b0, cur, 0);
    if (more) stageA(nxt, 0, koff);
    __builtin_amdgcn_s_barrier();
    LGKM0();
    __builtin_amdgcn_sched_barrier(0);
    mmac(0, 0, b0);
    __builtin_amdgcn_s_barrier();
    // P2
    loadB(b1, cur, 1);
    if (more) { stageB(nxt, 0, koff); VMCNT(6); } else { VMCNT(2); }
    __builtin_amdgcn_s_barrier();
    LGKM0();
    __builtin_amdgcn_sched_barrier(0);
    mmac(0, 2, b1);
    __builtin_amdgcn_s_barrier();
    // P3
    loadA(cur, 1);
    if (more) { stageB(nxt, 1, koff); VMCNT(6); } else { VMCNT(0); }
    __builtin_amdgcn_s_barrier();
    LGKM0();
    __builtin_amdgcn_sched_barrier(0);
    mmac(4, 0, b0);
    __builtin_amdgcn_s_barrier();
    // P4
    if (more) { stageA(nxt, 1, koff); VMCNT(4); }
    __builtin_amdgcn_s_barrier();
    mmac(4, 2, b1);
    __builtin_amdgcn_s_barrier();
  }

  const int sec = (EP == 0) ? (bn0 >> 10) : 0;
#pragma unroll
  for (int mt = 0; mt < 8; mt++) {
    int gr0 = bm0 + (mt >> 2) * 128 + (mt & 3) * 32 + wm * 16 + hi * 4;
#pragma unroll
    for (int nt = 0; nt < 4; nt++) {
      int gc = bn0 + (nt >> 1) * 128 + (nt & 1) * 64 + wn * 16 + lo;
      if constexpr (EP == 0) {
        int b_ = gr0 >> 11, t_ = gr0 & 2047;
        int nn = gc & 1023, h_ = nn >> 6, e_ = nn & 63;
        size_t bh = (size_t)(b_ * 16 + h_);
        if (sec == 2) {  // vT: 4 consecutive t per thread -> one 8B store
          u32x2 w;
          w.x = cvt_pk_bf16(acc[mt][nt][0], acc[mt][nt][1]);
          w.y = cvt_pk_bf16(acc[mt][nt][2], acc[mt][nt][3]);
          *(u32x2*)(out2 + (bh * 64 + e_) * 2048 + t_) = w;
        } else {
          float sc = (sec == 0) ? 0.0450842200f : 1.0f;  // q pre-scale D^-0.5*log2e
          u16* dst = (sec == 0) ? (u16*)out0 : out1;
#pragma unroll
          for (int j = 0; j < 4; j++)
            dst[(bh * 2048 + t_ + j) * 64 + e_] = f2bf(acc[mt][nt][j] * sc);
        }
      } else if constexpr (EP == 2) {
#pragma unroll
        for (int j = 0; j < 4; j++) {
          int gr = gr0 + j;
          float v = acc[mt][nt][j] + bias[gc];
          ((u16*)out0)[(size_t)gr * N + gc] = f2bf(fmaxf(v, 0.0f));
        }
      }
    }
  }
}

// ------------- 128x128 4-wave GEMM (half-scale port of the 8-phase template) -------------
// BM=BN=128, BK=64, 256 threads = 4 waves (2x2). Wave-out 64x64 via 32-row/col striping:
// out row = mt*32 + wm*16 + ..., col = nt*32 + wn*16 + ... -> every wave consumes both
// A-halves and both B-halves each K-tile (quadrant phases stay uniform across waves).
// LDS 64KB (2buf x 2half x [64][64] for A and B) -> 2 barrier-decoupled blocks/CU.
// Same counted-vmcnt discipline (units: 2 loads/half): prologue A0,B0,B1,A1 + vmcnt(4);
// steady P1 vmcnt(4) [B1(t) landed], P2 vmcnt(4) [A1(t)], P3 none, P4 vmcnt(4) [A0',B0'].
// Epilogue: out = acc + bias[col] + res[row][col] (fp32). No split-K, no partials.
__global__ __launch_bounds__(256, 2) void gemm128(const u16* __restrict__ A,
                                                  const u16* __restrict__ Bt,
                                                  int M, int N, int K,
                                                  const float* __restrict__ bias,
                                                  const float* __restrict__ res,
                                                  float* __restrict__ out) {
  __shared__ __align__(16) u16 lds[32768];  // A at 0, B at 16384 (u16 units)
  const int tid = threadIdx.x;
  const int lane = tid & 63, wave = tid >> 6;
  const int lo = lane & 15, hi = lane >> 4;
  const int wm = wave >> 1, wn = wave & 1;
  // XCD swizzle
  int gx = gridDim.x;
  int lin = blockIdx.y * gx + blockIdx.x;
  int nwg = gx * gridDim.y;
  int cpx = nwg >> 3;
  int swz = (lin & 7) * cpx + (lin >> 3);
  int bm0 = (swz / gx) * 128, bn0 = (swz % gx) * 128;
  int T = K >> 6;

  // staging: half = [64 rows][64 k] = 512 x 16B chunks; thread covers chunks tid, tid+256
  int rs_ = tid >> 3, ss_ = (tid & 7) ^ (rs_ & 7);
  const u16* srcA = A + (size_t)(bm0 + rs_) * K + ss_ * 8;
  const u16* srcB = Bt + (size_t)(bn0 + rs_) * K + ss_ * 8;
  const size_t i1 = (size_t)32 * K;   // chunk-set 1: +32 rows
  const size_t h1 = (size_t)64 * K;   // half 1: +64 rows
  const int dst0 = wave * 512;        // u16 offsets within 4096-u16 half-buffer
  const int dst1 = 2048 + wave * 512;

  const int sp0 = (hi ^ (lo & 7)) * 8;

  f32x4 acc[4][4] = {};
  bf16x8 a[4][2], b[4][2];

  auto stageA = [&](int buf, int h, int koff) {
    const u16* s = srcA + koff + (h ? h1 : 0);
    u16* d = lds + (buf * 2 + h) * 4096;
    gload_lds16(s, d + dst0);
    gload_lds16(s + i1, d + dst1);
  };
  auto stageB = [&](int buf, int h, int koff) {
    const u16* s = srcB + koff + (h ? h1 : 0);
    u16* d = lds + 16384 + (buf * 2 + h) * 4096;
    gload_lds16(s, d + dst0);
    gload_lds16(s + i1, d + dst1);
  };
  auto loadAh = [&](int buf, int h) {  // fills a[2h], a[2h+1]
    const u16* base = lds + (buf * 2 + h) * 4096;
#pragma unroll
    for (int m = 0; m < 2; m++) {
      int lr = m * 32 + wm * 16 + lo;
      a[h * 2 + m][0] = *(const bf16x8*)(base + lr * 64 + sp0);
      a[h * 2 + m][1] = *(const bf16x8*)(base + lr * 64 + (sp0 ^ 32));
    }
  };
  auto loadBh = [&](int buf, int h) {  // fills b[2h], b[2h+1]
    const u16* base = lds + 16384 + (buf * 2 + h) * 4096;
#pragma unroll
    for (int n = 0; n < 2; n++) {
      int lr = n * 32 + wn * 16 + lo;
      b[h * 2 + n][0] = *(const bf16x8*)(base + lr * 64 + sp0);
      b[h * 2 + n][1] = *(const bf16x8*)(base + lr * 64 + (sp0 ^ 32));
    }
  };
  auto mmac = [&](int mb, int nb) {  // 8 MFMA: m in {mb,mb+1} x n in {nb,nb+1} x 2kk
    __builtin_amdgcn_s_setprio(1);
#pragma unroll
    for (int m = 0; m < 2; m++)
#pragma unroll
      for (int n = 0; n < 2; n++) {
        acc[mb + m][nb + n] = MFMA16(a[mb + m][0], b[nb + n][0], acc[mb + m][nb + n]);
        acc[mb + m][nb + n] = MFMA16(a[mb + m][1], b[nb + n][1], acc[mb + m][nb + n]);
      }
    __builtin_amdgcn_s_setprio(0);
  };

  // prologue: tile 0, order A0,B0,B1,A1 (2 loads each); A0,B0 confirmed, B1,A1 in flight
  stageA(0, 0, 0); stageB(0, 0, 0); stageB(0, 1, 0); stageA(0, 1, 0);
  VMCNT(4);
  __builtin_amdgcn_s_barrier();

  for (int t = 0; t < T; ++t) {
    int cur = t & 1, nxt = cur ^ 1;
    bool more = (t + 1 < T);
    int koff = (t + 1) * 64;
    // P1: consume A-h0 x B-h0 (a0,a1 x b0,b1)
    loadAh(cur, 0); loadBh(cur, 0);
    if (more) { stageA(nxt, 0, koff); VMCNT(4); } else { VMCNT(2); }
    __builtin_amdgcn_s_barrier();
    LGKM0();
    __builtin_amdgcn_sched_barrier(0);
    mmac(0, 0);
    __builtin_amdgcn_s_barrier();
    // P2: consume B-h1 (b2,b3)
    loadBh(cur, 1);
    if (more) { stageB(nxt, 0, koff); VMCNT(4); } else { VMCNT(0); }
    __builtin_amdgcn_s_barrier();
    LGKM0();
    __builtin_amdgcn_sched_barrier(0);
    mmac(0, 2);
    __builtin_amdgcn_s_barrier();
    // P3: consume A-h1 (a2,a3)
    loadAh(cur, 1);
    if (more) stageB(nxt, 1, koff);
    __builtin_amdgcn_s_barrier();
    LGKM0();
    __builtin_amdgcn_sched_barrier(0);
    mmac(2, 0);
    __builtin_amdgcn_s_barrier();
    // P4
    if (more) { stageA(nxt, 1, koff); VMCNT(4); }
    __builtin_amdgcn_s_barrier();
    mmac(2, 2);
    __builtin_amdgcn_s_barrier();
  }

  // epilogue: out = acc + bias + res (fp32)
#pragma unroll
  for (int mt = 0; mt < 4; mt++) {
    int gr0 = bm0 + mt * 32 + wm * 16 + hi * 4;
#pragma unroll
    for (int nt = 0; nt < 4; nt++) {
      int gc = bn0 + nt * 32 + wn * 16 + lo;
      float bb = bias[gc];
#pragma unroll
      for (int j = 0; j < 4; j++) {
        int gr = gr0 + j;
        out[(size_t)gr * N + gc] = acc[mt][nt][j] + bb + res[(size_t)gr * N + gc];
      }
    }
  }
}

// ------------------------- causal flash attention (paired Q-tiles) -------------------------
// r8 structure (measured best). Block i of 16 handles Q-tiles (31-i) [waves 0-3] and
// (i) [waves 4-7] sharing one double-buffered K/V staging pipeline.
__global__ __launch_bounds__(512, 4) void attn_kernel(const u16* __restrict__ q,
                                                      const u16* __restrict__ k,
                                                      const u16* __restrict__ vt,
                                                      u16* __restrict__ o) {
  __shared__ __align__(16) u16 Ks[2][64 * 64];
  __shared__ __align__(16) u16 Vs[2][64 * 64];
  __shared__ __align__(16) u16 Ps[8][16 * 72];
  int bh = blockIdx.y;
  int pi = blockIdx.x;  // 0..15
  int tid = threadIdx.x, lane = tid & 63, wave = tid >> 6;
  int lo = lane & 15, hi = lane >> 4;
  int grp = wave >> 2;                      // 0: long tile, 1: short tile
  int qblk_w = grp ? pi : (31 - pi);
  int qb0 = qblk_w * 64;
  int nkb = 32 - pi;                        // loop length = long tile's KV count
  const u16* qbase = q + (size_t)bh * 2048 * 64;
  const u16* kbase = k + (size_t)bh * 2048 * 64;
  const u16* vbase = vt + (size_t)bh * 64 * 2048;

  int srow = tid >> 3;
  int ssl = (tid & 7) ^ (srow & 7);         // both-sides XOR swizzle
  int kOff = srow * 64 + ssl * 8;
  int vOff = srow * 2048 + ssl * 8;

  int qrow = qb0 + (wave & 3) * 16 + lo;
  bf16x8 qf0 = *(const bf16x8*)(qbase + (size_t)qrow * 64 + hi * 8);
  bf16x8 qf1 = *(const bf16x8*)(qbase + (size_t)qrow * 64 + 32 + hi * 8);

  float l_r = 0.0f;
  f32x4 of[4] = {};
  u16* Pw = Ps[wave];

  auto stage = [&](int b, int kb) {
    gload_lds16(kbase + (size_t)kb * 4096 + kOff, Ks[b] + wave * 512);
    gload_lds16(vbase + kb * 64 + vOff, Vs[b] + wave * 512);
  };

  stage(0, 0);
  __syncthreads();

  for (int kb = 0; kb < nkb; kb++) {
    int cur = kb & 1;
    if (kb + 1 < nkb) stage(cur ^ 1, kb + 1);
    if (kb <= qblk_w) {
      const u16* Kb = Ks[cur];
      const u16* Vb = Vs[cur];
      f32x4 s4[4] = {};
#pragma unroll
      for (int nt = 0; nt < 4; nt++) {
        int r = nt * 16 + lo, rw = r & 7;
        bf16x8 kf0 = *(const bf16x8*)(Kb + r * 64 + ((hi ^ rw) << 3));
        bf16x8 kf1 = *(const bf16x8*)(Kb + r * 64 + (((hi + 4) ^ rw) << 3));
        s4[nt] = MFMA16(kf0, qf0, s4[nt]);
        s4[nt] = MFMA16(kf1, qf1, s4[nt]);
      }
      float rs = 0.0f;
      bool diag = (kb == qblk_w);
#pragma unroll
      for (int nt = 0; nt < 4; nt++) {
        float e0, e1, e2, e3;
        if (diag) {
          int key = kb * 64 + nt * 16 + hi * 4;
          e0 = (key     > qrow) ? 0.0f : __builtin_amdgcn_exp2f(s4[nt][0]);
          e1 = (key + 1 > qrow) ? 0.0f : __builtin_amdgcn_exp2f(s4[nt][1]);
          e2 = (key + 2 > qrow) ? 0.0f : __builtin_amdgcn_exp2f(s4[nt][2]);
          e3 = (key + 3 > qrow) ? 0.0f : __builtin_amdgcn_exp2f(s4[nt][3]);
        } else {
          e0 = __builtin_amdgcn_exp2f(s4[nt][0]);
          e1 = __builtin_amdgcn_exp2f(s4[nt][1]);
          e2 = __builtin_amdgcn_exp2f(s4[nt][2]);
          e3 = __builtin_amdgcn_exp2f(s4[nt][3]);
        }
        rs += (e0 + e1) + (e2 + e3);
        u32x2 w;
        w.x = cvt_pk_bf16(e0, e1);
        w.y = cvt_pk_bf16(e2, e3);
        *(u32x2*)(Pw + lo * 72 + nt * 16 + hi * 4) = w;
      }
      rs += __shfl_xor(rs, 16);
      rs += __shfl_xor(rs, 32);
      l_r += rs;
      bf16x8 pb0 = *(const bf16x8*)(Pw + lo * 72 + hi * 8);
      bf16x8 pb1 = *(const bf16x8*)(Pw + lo * 72 + 32 + hi * 8);
#pragma unroll
      for (int et = 0; et < 4; et++) {
        int e = et * 16 + lo, ew = e & 7;
        bf16x8 v0 = *(const bf16x8*)(Vb + e * 64 + ((hi ^ ew) << 3));
        bf16x8 v1 = *(const bf16x8*)(Vb + e * 64 + (((hi + 4) ^ ew) << 3));
        of[et] = MFMA16(v0, pb0, of[et]);
        of[et] = MFMA16(v1, pb1, of[et]);
      }
    }
    __syncthreads();
  }
  int hh = bh & 15, bb = bh >> 4;
  float inv = 1.0f / l_r;
  size_t obase = ((size_t)(bb * 2048 + qrow)) * 1024 + hh * 64 + hi * 4;
#pragma unroll
  for (int et = 0; et < 4; et++) {
    u32x2 w;
    w.x = cvt_pk_bf16(of[et][0] * inv, of[et][1] * inv);
    w.y = cvt_pk_bf16(of[et][2] * inv, of[et][3] * inv);
    *(u32x2*)(o + obase + et * 16) = w;
  }
}

extern "C" void kernel_launch(void* const* d_in, const int* in_sizes, int n_in,
                              void* d_out, int out_size, void* d_ws, size_t ws_size,
                              hipStream_t stream) {
  const float* x = (const float*)d_in[0];
  const float* Wq = (const float*)d_in[1];
  const float* Wk = (const float*)d_in[2];
  const float* Wv = (const float*)d_in[3];
  const float* Wo = (const float*)d_in[4];
  const float* bo = (const float*)d_in[5];
  const float* W1 = (const float*)d_in[6];
  const float* b1 = (const float*)d_in[7];
  const float* W2 = (const float*)d_in[8];
  const float* b2 = (const float*)d_in[9];
  const float* g1 = (const float*)d_in[10];
  const float* be1 = (const float*)d_in[11];
  const float* g2 = (const float*)d_in[12];
  const float* be2 = (const float*)d_in[13];
  float* out = (float*)d_out;
  char* ws = (char*)d_ws;
  const size_t MB = 1024ull * 1024ull;

  // workspace map (72MB peak), all transposes materialized up front:
  //  0- 8 : h (ln1) -> o (attn out)          [o dead after Wo gemm]
  //  8-14 : BtQKV [dead after QKV gemm]  -> h2 (ln2 out, 8-16)
  // 14-16 : WoT   [dead after Wo gemm]   -> (h2 tail)
  // 16-24 : W1T   [dead after FFN1]
  // 32-40 : qb    [dead after attn]      -> yb (32-64, FFN1 out)
  // 40-48 : kb    [dead after attn]
  // 48-56 : vtb   [dead after attn]
  // 64-72 : W2T   [dead after FFN2]
  u16* h = (u16*)(ws + 0);
  u16* o = h;
  u16* BtQKV = (u16*)(ws + 8 * MB);
  u16* WoT = (u16*)(ws + 14 * MB);
  u16* W1T = (u16*)(ws + 16 * MB);
  u16* W2T = (u16*)(ws + 64 * MB);
  u16* qb = (u16*)(ws + 32 * MB);
  u16* kb = (u16*)(ws + 40 * MB);
  u16* vtb = (u16*)(ws + 48 * MB);
  u16* h2 = (u16*)(ws + 8 * MB);
  u16* yb = (u16*)(ws + 32 * MB);

  // 1. prep: LN1 + all weight transposes (one launch)
  prep_kernel<<<16384, 256, 0, stream>>>(x, g1, be1, h, Wq, Wk, Wv, BtQKV,
                                         Wo, WoT, W1, W1T, W2, W2T);
  // 2. QKV projection: [4096][1024] x [3072][1024]^T, scatter epilogue (q pre-scaled)
  gemm8p<0><<<dim3(12, 16), 512, 0, stream>>>(h, BtQKV, 4096, 3072, 1024, 1024,
                                              (void*)qb, kb, vtb, nullptr);
  // 3. causal attention -> o (bf16 [B][T][D]); 16 mirrored-paired blocks x 32 bh
  attn_kernel<<<dim3(16, 32), 512, 0, stream>>>(qb, kb, vtb, o);
  // 4. Wo (no split-K): out = x + o@Wo + bo (fp32), 128^2 tiles, 256 blocks
  gemm128<<<dim3(8, 32), 256, 0, stream>>>(o, WoT, 4096, 1024, 1024, bo, x, out);
  // 5. LN2: out -> h2 (bf16)
  ln_kernel<<<4096, 256, 0, stream>>>(out, g2, be2, h2);
  // 6. FFN1: y = relu(h2@W1 + b1) (bf16), 256^2 tiles
  gemm8p<2><<<dim3(16, 16), 512, 0, stream>>>(h2, W1T, 4096, 4096, 1024, 1024,
                                              (void*)yb, nullptr, nullptr, b1);
  // 7. FFN2 (no split-K): out = out + y@W2 + b2 (fp32), 128^2 tiles, K=4096
  gemm128<<<dim3(8, 32), 256, 0, stream>>>(yb, W2T, 4096, 1024, 4096, b2, out, out);
}

// Round 13
// 197.586 us; speedup vs baseline: 1.1860x; 1.0515x over previous
//
#include <hip/hip_runtime.h>
#include <stdint.h>

typedef unsigned short u16;
typedef __attribute__((ext_vector_type(8))) short bf16x8;
typedef __attribute__((ext_vector_type(4))) float f32x4;
typedef __attribute__((ext_vector_type(4))) unsigned int u32x4;
typedef __attribute__((ext_vector_type(2))) unsigned int u32x2;
typedef __attribute__((ext_vector_type(4))) unsigned short u16x4;

#define MFMA16(a, b, c) __builtin_amdgcn_mfma_f32_16x16x32_bf16(a, b, c, 0, 0, 0)
#define VMCNT(N) asm volatile("s_waitcnt vmcnt(" #N ")" ::: "memory")
#define LGKM0() asm volatile("s_waitcnt lgkmcnt(0)" ::: "memory")

__device__ __forceinline__ u16 f2bf(float f) {
  union { float f; uint32_t u; } v; v.f = f;
  uint32_t r = v.u + 0x7FFFu + ((v.u >> 16) & 1u);
  return (u16)(r >> 16);
}

__device__ __forceinline__ float bf2f(u16 u) {
  union { uint32_t u; float f; } v; v.u = ((uint32_t)u) << 16;
  return v.f;
}

__device__ __forceinline__ uint32_t cvt_pk_bf16(float a, float b) {
  uint32_t r;
  asm("v_cvt_pk_bf16_f32 %0, %1, %2" : "=v"(r) : "v"(a), "v"(b));
  return r;
}

// async global->LDS, 16B per lane. LDS dest is wave-uniform base + lane*16.
__device__ __forceinline__ void gload_lds16(const u16* g, u16* l) {
  __builtin_amdgcn_global_load_lds((const __attribute__((address_space(1))) void*)(g),
                                   (__attribute__((address_space(3))) void*)(l), 16, 0, 0);
}

// ------------- prep mega-kernel: LN1 + all weight transposes, one launch -------------
__global__ __launch_bounds__(256) void prep_kernel(
    const float* __restrict__ x, const float* __restrict__ g1,
    const float* __restrict__ be1, u16* __restrict__ h,
    const float* __restrict__ Wq, const float* __restrict__ Wk,
    const float* __restrict__ Wv, u16* __restrict__ BtQKV,
    const float* __restrict__ Wo, u16* __restrict__ WoT,
    const float* __restrict__ W1, u16* __restrict__ W1T,
    const float* __restrict__ W2, u16* __restrict__ W2T) {
  __shared__ float tile[32][33];
  __shared__ float red[8];
  int bid = blockIdx.x, tid = threadIdx.x;
  if (bid < 4096) {
    int row = bid;
    float4 v = ((const float4*)(x + (size_t)row * 1024))[tid];
    float s = v.x + v.y + v.z + v.w;
    float ss = v.x * v.x + v.y * v.y + v.z * v.z + v.w * v.w;
#pragma unroll
    for (int m = 1; m < 64; m <<= 1) { s += __shfl_xor(s, m); ss += __shfl_xor(ss, m); }
    int wave = tid >> 6, lane = tid & 63;
    if (lane == 0) { red[wave] = s; red[4 + wave] = ss; }
    __syncthreads();
    s = red[0] + red[1] + red[2] + red[3];
    ss = red[4] + red[5] + red[6] + red[7];
    float mean = s * (1.0f / 1024.0f);
    float var = ss * (1.0f / 1024.0f) - mean * mean;
    float rstd = rsqrtf(var + 1e-5f);
    float4 gv = ((const float4*)g1)[tid];
    float4 bv = ((const float4*)be1)[tid];
    u16x4 o;
    o.x = f2bf((v.x - mean) * rstd * gv.x + bv.x);
    o.y = f2bf((v.y - mean) * rstd * gv.y + bv.y);
    o.z = f2bf((v.z - mean) * rstd * gv.z + bv.z);
    o.w = f2bf((v.w - mean) * rstd * gv.w + bv.w);
    *(u16x4*)(h + (size_t)row * 1024 + tid * 4) = o;
    return;
  }
  const float* I;
  u16* O;
  int K, N, n0, k0;
  if (bid < 7168) {
    int idx = bid - 4096;
    int bz = idx >> 6, by = (idx >> 1) & 31, bx = idx & 1;
    int ww = bz >> 4, head = bz & 15;
    I = ((ww == 0) ? Wq : (ww == 1) ? Wk : Wv) + (size_t)head * 65536;
    O = BtQKV + (size_t)ww * 1048576 + (size_t)head * 65536;
    K = 1024; N = 64; n0 = bx * 32; k0 = by * 32;
  } else if (bid < 8192) {
    int idx = bid - 7168;
    I = Wo; O = WoT; K = 1024; N = 1024;
    n0 = (idx & 31) * 32; k0 = (idx >> 5) * 32;
  } else if (bid < 12288) {
    int idx = bid - 8192;
    I = W1; O = W1T; K = 1024; N = 4096;
    n0 = (idx & 127) * 32; k0 = (idx >> 7) * 32;
  } else {
    int idx = bid - 12288;
    I = W2; O = W2T; K = 4096; N = 1024;
    n0 = (idx & 31) * 32; k0 = (idx >> 5) * 32;
  }
  int tx = tid & 31, ty = tid >> 5;
#pragma unroll
  for (int i = 0; i < 4; i++)
    tile[ty + i * 8][tx] = I[(size_t)(k0 + ty + i * 8) * N + n0 + tx];
  __syncthreads();
#pragma unroll
  for (int i = 0; i < 4; i++)
    O[(size_t)(n0 + ty + i * 8) * K + k0 + tx] = f2bf(tile[tx][ty + i * 8]);
}

// ---------------- LayerNorm: fp32 [rows][1024] -> bf16 [rows][1024] ----------------
__global__ __launch_bounds__(256) void ln_kernel(const float* __restrict__ x,
                                                 const float* __restrict__ g,
                                                 const float* __restrict__ beta,
                                                 u16* __restrict__ out) {
  int row = blockIdx.x;
  int tid = threadIdx.x;
  float4 v = ((const float4*)(x + (size_t)row * 1024))[tid];
  float s = v.x + v.y + v.z + v.w;
  float ss = v.x * v.x + v.y * v.y + v.z * v.z + v.w * v.w;
#pragma unroll
  for (int m = 1; m < 64; m <<= 1) { s += __shfl_xor(s, m); ss += __shfl_xor(ss, m); }
  __shared__ float red[8];
  int wave = tid >> 6, lane = tid & 63;
  if (lane == 0) { red[wave] = s; red[4 + wave] = ss; }
  __syncthreads();
  s = red[0] + red[1] + red[2] + red[3];
  ss = red[4] + red[5] + red[6] + red[7];
  float mean = s * (1.0f / 1024.0f);
  float var = ss * (1.0f / 1024.0f) - mean * mean;
  float rstd = rsqrtf(var + 1e-5f);
  float4 gv = ((const float4*)g)[tid];
  float4 bv = ((const float4*)beta)[tid];
  u16x4 o;
  o.x = f2bf((v.x - mean) * rstd * gv.x + bv.x);
  o.y = f2bf((v.y - mean) * rstd * gv.y + bv.y);
  o.z = f2bf((v.z - mean) * rstd * gv.z + bv.z);
  o.w = f2bf((v.w - mean) * rstd * gv.w + bv.w);
  *(u16x4*)(out + (size_t)row * 1024 + tid * 4) = o;
}

// ---------------- 256x256 8-phase GEMM: C[M][N] = A[M][K] * Bt[N][K]^T ----------------
// m201-conformant schedule. EP 0: QKV scatter; EP 2: relu+bias bf16 (FFN1).
template <int EP>
__global__ __launch_bounds__(512, 2) void gemm8p(const u16* __restrict__ A,
                                                 const u16* __restrict__ Bt,
                                                 int M, int N, int K, int KS,
                                                 void* __restrict__ out0,
                                                 u16* __restrict__ out1,
                                                 u16* __restrict__ out2,
                                                 const float* __restrict__ bias) {
  __shared__ __align__(16) u16 lds[65536];  // A at 0, B at 32768 (u16 units)
  const int tid = threadIdx.x;
  const int lane = tid & 63, wave = tid >> 6;
  const int lo = lane & 15, hi = lane >> 4;
  const int wm = wave >> 2, wn = wave & 3;
  // XCD swizzle
  int gx = gridDim.x;
  int lin = blockIdx.y * gx + blockIdx.x;
  int nwg = gx * gridDim.y;
  int cpx = nwg >> 3;
  int swz = (lin & 7) * cpx + (lin >> 3);
  int bm0 = (swz / gx) * 256, bn0 = (swz % gx) * 256;
  int kbeg = blockIdx.z * KS;
  int T = KS >> 6;

  int rs_ = tid >> 3, ss_ = (tid & 7) ^ (rs_ & 7);
  const u16* srcA = A + (size_t)(bm0 + rs_) * K + kbeg + ss_ * 8;
  const u16* srcB = Bt + (size_t)(bn0 + rs_) * K + kbeg + ss_ * 8;
  const size_t i1 = (size_t)64 * K;
  const size_t h1 = (size_t)128 * K;
  const int dst0 = wave * 512;
  const int dst1 = 4096 + wave * 512;

  const int rpA = wm * 16 + lo;
  const int rpB = wn * 16 + lo;
  const int sp0 = (hi ^ (lo & 7)) * 8;

  f32x4 acc[8][4] = {};
  bf16x8 a[4][2], b0[2][2], b1[2][2];

  auto stageA = [&](int buf, int h, int koff) {
    const u16* s = srcA + koff + (h ? h1 : 0);
    u16* d = lds + (buf * 2 + h) * 8192;
    gload_lds16(s, d + dst0);
    gload_lds16(s + i1, d + dst1);
  };
  auto stageB = [&](int buf, int h, int koff) {
    const u16* s = srcB + koff + (h ? h1 : 0);
    u16* d = lds + 32768 + (buf * 2 + h) * 8192;
    gload_lds16(s, d + dst0);
    gload_lds16(s + i1, d + dst1);
  };
  auto loadA = [&](int buf, int h) {
    const u16* base = lds + (buf * 2 + h) * 8192 + rpA * 64;
#pragma unroll
    for (int m = 0; m < 4; m++) {
      a[m][0] = *(const bf16x8*)(base + m * 2048 + sp0);
      a[m][1] = *(const bf16x8*)(base + m * 2048 + (sp0 ^ 32));
    }
  };
  auto loadB = [&](bf16x8 (&bb)[2][2], int buf, int g) {
    const u16* base = lds + 32768 + (buf * 2 + g) * 8192 + rpB * 64;
#pragma unroll
    for (int n = 0; n < 2; n++) {
      bb[n][0] = *(const bf16x8*)(base + n * 4096 + sp0);
      bb[n][1] = *(const bf16x8*)(base + n * 4096 + (sp0 ^ 32));
    }
  };
  auto mmac = [&](int mh, int np, bf16x8 (&bb)[2][2]) {
    __builtin_amdgcn_s_setprio(1);
#pragma unroll
    for (int m = 0; m < 4; m++)
#pragma unroll
      for (int n = 0; n < 2; n++) {
        acc[mh + m][np + n] = MFMA16(a[m][0], bb[n][0], acc[mh + m][np + n]);
        acc[mh + m][np + n] = MFMA16(a[m][1], bb[n][1], acc[mh + m][np + n]);
      }
    __builtin_amdgcn_s_setprio(0);
  };

  stageA(0, 0, 0); stageB(0, 0, 0); stageB(0, 1, 0); stageA(0, 1, 0);
  VMCNT(4);
  __builtin_amdgcn_s_barrier();

  for (int t = 0; t < T; ++t) {
    int cur = t & 1, nxt = cur ^ 1;
    bool more = (t + 1 < T);
    int koff = (t + 1) * 64;
    // P1
    loadA(cur, 0); loadB(b0, cur, 0);
    if (more) stageA(nxt, 0, koff);
    __builtin_amdgcn_s_barrier();
    LGKM0();
    __builtin_amdgcn_sched_barrier(0);
    mmac(0, 0, b0);
    __builtin_amdgcn_s_barrier();
    // P2
    loadB(b1, cur, 1);
    if (more) { stageB(nxt, 0, koff); VMCNT(6); } else { VMCNT(2); }
    __builtin_amdgcn_s_barrier();
    LGKM0();
    __builtin_amdgcn_sched_barrier(0);
    mmac(0, 2, b1);
    __builtin_amdgcn_s_barrier();
    // P3
    loadA(cur, 1);
    if (more) { stageB(nxt, 1, koff); VMCNT(6); } else { VMCNT(0); }
    __builtin_amdgcn_s_barrier();
    LGKM0();
    __builtin_amdgcn_sched_barrier(0);
    mmac(4, 0, b0);
    __builtin_amdgcn_s_barrier();
    // P4
    if (more) { stageA(nxt, 1, koff); VMCNT(4); }
    __builtin_amdgcn_s_barrier();
    mmac(4, 2, b1);
    __builtin_amdgcn_s_barrier();
  }

  const int sec = (EP == 0) ? (bn0 >> 10) : 0;
#pragma unroll
  for (int mt = 0; mt < 8; mt++) {
    int gr0 = bm0 + (mt >> 2) * 128 + (mt & 3) * 32 + wm * 16 + hi * 4;
#pragma unroll
    for (int nt = 0; nt < 4; nt++) {
      int gc = bn0 + (nt >> 1) * 128 + (nt & 1) * 64 + wn * 16 + lo;
      if constexpr (EP == 0) {
        int b_ = gr0 >> 11, t_ = gr0 & 2047;
        int nn = gc & 1023, h_ = nn >> 6, e_ = nn & 63;
        size_t bh = (size_t)(b_ * 16 + h_);
        if (sec == 2) {  // vT: 4 consecutive t per thread -> one 8B store
          u32x2 w;
          w.x = cvt_pk_bf16(acc[mt][nt][0], acc[mt][nt][1]);
          w.y = cvt_pk_bf16(acc[mt][nt][2], acc[mt][nt][3]);
          *(u32x2*)(out2 + (bh * 64 + e_) * 2048 + t_) = w;
        } else {
          float sc = (sec == 0) ? 0.0450842200f : 1.0f;  // q pre-scale D^-0.5*log2e
          u16* dst = (sec == 0) ? (u16*)out0 : out1;
#pragma unroll
          for (int j = 0; j < 4; j++)
            dst[(bh * 2048 + t_ + j) * 64 + e_] = f2bf(acc[mt][nt][j] * sc);
        }
      } else if constexpr (EP == 2) {
#pragma unroll
        for (int j = 0; j < 4; j++) {
          int gr = gr0 + j;
          float v = acc[mt][nt][j] + bias[gc];
          ((u16*)out0)[(size_t)gr * N + gc] = f2bf(fmaxf(v, 0.0f));
        }
      }
    }
  }
}

// ---- 128x128 8-wave 4-phase GEMM (BK=128), direct clone of gemm8p's schedule ----
// 512 threads = 8 waves (4M x 2N), wave-out 32 rows x 64 cols (acc[2][4]).
// LDS 128KB: per matrix 2buf x 2half x [64 rows][128 k] (16KB sets, 2 loads/thread).
// A-half h holds global rows h*64..h*64+63 (consumed as mt=h); B-half g holds
// cols g*64.. (nt in {2g, 2g+1}). Rows are 16 slots of 16B; swizzle slot^(row&15)
// both sides -> ds_read_b128 2-way bank alias (free). Same vmcnt ladder as gemm8p:
// P1 none / P2 vmcnt(6) / P3 vmcnt(6) / P4 vmcnt(4); prologue vmcnt(4).
// Epilogue: out = acc + bias[col] + res (fp32). Grid 256 blocks -> 2 waves/SIMD.
__global__ __launch_bounds__(512, 2) void gemm128(const u16* __restrict__ A,
                                                  const u16* __restrict__ Bt,
                                                  int M, int N, int K,
                                                  const float* __restrict__ bias,
                                                  const float* __restrict__ res,
                                                  float* __restrict__ out) {
  __shared__ __align__(16) u16 lds[65536];  // A at 0, B at 32768 (u16 units)
  const int tid = threadIdx.x;
  const int lane = tid & 63, wave = tid >> 6;
  const int lo = lane & 15, hi = lane >> 4;
  const int wm = wave >> 1, wn = wave & 1;
  // XCD swizzle
  int gx = gridDim.x;
  int lin = blockIdx.y * gx + blockIdx.x;
  int nwg = gx * gridDim.y;
  int cpx = nwg >> 3;
  int swz = (lin & 7) * cpx + (lin >> 3);
  int bm0 = (swz / gx) * 128, bn0 = (swz % gx) * 128;
  int T = K >> 7;  // BK = 128

  // staging: set = [64 rows][128 k] = 1024 x 16B chunks; thread covers tid, tid+512
  int rs_ = tid >> 4, ss_ = (tid & 15) ^ (rs_ & 15);
  const u16* srcA = A + (size_t)(bm0 + rs_) * K + ss_ * 8;
  const u16* srcB = Bt + (size_t)(bn0 + rs_) * K + ss_ * 8;
  const size_t i1 = (size_t)32 * K;   // chunk-set 1: +32 rows
  const size_t h1 = (size_t)64 * K;   // half 1: +64 rows
  const int dst0 = wave * 512;
  const int dst1 = 4096 + wave * 512;

  const int rA = wm * 16 + lo;        // local row within A-half
  const int cB = wn * 16 + lo;        // local col base within B-half (nt&1 adds 32)

  f32x4 acc[2][4] = {};
  bf16x8 a[4], b0[2][4], b1[2][4];

  auto stageA = [&](int buf, int h, int koff) {
    const u16* s = srcA + koff + (h ? h1 : 0);
    u16* d = lds + (buf * 2 + h) * 8192;
    gload_lds16(s, d + dst0);
    gload_lds16(s + i1, d + dst1);
  };
  auto stageB = [&](int buf, int h, int koff) {
    const u16* s = srcB + koff + (h ? h1 : 0);
    u16* d = lds + 32768 + (buf * 2 + h) * 8192;
    gload_lds16(s, d + dst0);
    gload_lds16(s + i1, d + dst1);
  };
  auto loadA_ = [&](int buf, int h) {
    const u16* base = lds + (buf * 2 + h) * 8192 + rA * 128;
#pragma unroll
    for (int kk = 0; kk < 4; kk++)
      a[kk] = *(const bf16x8*)(base + (((kk * 4 + hi) ^ lo) << 3));
  };
  auto loadB_ = [&](bf16x8 (&bb)[2][4], int buf, int g) {
    const u16* base = lds + 32768 + (buf * 2 + g) * 8192 + cB * 128;
#pragma unroll
    for (int n = 0; n < 2; n++)
#pragma unroll
      for (int kk = 0; kk < 4; kk++)
        bb[n][kk] = *(const bf16x8*)(base + n * 4096 + (((kk * 4 + hi) ^ lo) << 3));
  };
  auto mmac = [&](int mt, int g, bf16x8 (&bb)[2][4]) {
    __builtin_amdgcn_s_setprio(1);
#pragma unroll
    for (int n = 0; n < 2; n++)
#pragma unroll
      for (int kk = 0; kk < 4; kk++)
        acc[mt][g * 2 + n] = MFMA16(a[kk], bb[n][kk], acc[mt][g * 2 + n]);
    __builtin_amdgcn_s_setprio(0);
  };

  // prologue: tile 0, order Ah0,Bh0,Bh1,Ah1; Ah0,Bh0 confirmed, Bh1,Ah1 in flight
  stageA(0, 0, 0); stageB(0, 0, 0); stageB(0, 1, 0); stageA(0, 1, 0);
  VMCNT(4);
  __builtin_amdgcn_s_barrier();

  for (int t = 0; t < T; ++t) {
    int cur = t & 1, nxt = cur ^ 1;
    bool more = (t + 1 < T);
    int koff = (t + 1) * 128;
    // P1: a = A-h0, b0 = B-h0; MFMA mt0 x nt{0,1}
    loadA_(cur, 0); loadB_(b0, cur, 0);
    if (more) stageA(nxt, 0, koff);
    __builtin_amdgcn_s_barrier();
    LGKM0();
    __builtin_amdgcn_sched_barrier(0);
    mmac(0, 0, b0);
    __builtin_amdgcn_s_barrier();
    // P2: b1 = B-h1; MFMA mt0 x nt{2,3}
    loadB_(b1, cur, 1);
    if (more) { stageB(nxt, 0, koff); VMCNT(6); } else { VMCNT(2); }
    __builtin_amdgcn_s_barrier();
    LGKM0();
    __builtin_amdgcn_sched_barrier(0);
    mmac(0, 1, b1);
    __builtin_amdgcn_s_barrier();
    // P3: a = A-h1; MFMA mt1 x nt{0,1} (reuse b0)
    loadA_(cur, 1);
    if (more) { stageB(nxt, 1, koff); VMCNT(6); } else { VMCNT(0); }
    __builtin_amdgcn_s_barrier();
    LGKM0();
    __builtin_amdgcn_sched_barrier(0);
    mmac(1, 0, b0);
    __builtin_amdgcn_s_barrier();
    // P4: MFMA mt1 x nt{2,3} (reuse b1)
    if (more) { stageA(nxt, 1, koff); VMCNT(4); }
    __builtin_amdgcn_s_barrier();
    mmac(1, 1, b1);
    __builtin_amdgcn_s_barrier();
  }

  // epilogue: out = acc + bias + res (fp32)
#pragma unroll
  for (int mt = 0; mt < 2; mt++) {
    int gr0 = bm0 + mt * 64 + wm * 16 + hi * 4;
#pragma unroll
    for (int nt = 0; nt < 4; nt++) {
      int gc = bn0 + nt * 32 + wn * 16 + lo;
      float bb = bias[gc];
#pragma unroll
      for (int j = 0; j < 4; j++) {
        int gr = gr0 + j;
        out[(size_t)gr * N + gc] = acc[mt][nt][j] + bb + res[(size_t)gr * N + gc];
      }
    }
  }
}

// ------------------------- causal flash attention (paired Q-tiles) -------------------------
// r8 structure (measured best). Block i of 16 handles Q-tiles (31-i) [waves 0-3] and
// (i) [waves 4-7] sharing one double-buffered K/V staging pipeline.
__global__ __launch_bounds__(512, 4) void attn_kernel(const u16* __restrict__ q,
                                                      const u16* __restrict__ k,
                                                      const u16* __restrict__ vt,
                                                      u16* __restrict__ o) {
  __shared__ __align__(16) u16 Ks[2][64 * 64];
  __shared__ __align__(16) u16 Vs[2][64 * 64];
  __shared__ __align__(16) u16 Ps[8][16 * 72];
  int bh = blockIdx.y;
  int pi = blockIdx.x;  // 0..15
  int tid = threadIdx.x, lane = tid & 63, wave = tid >> 6;
  int lo = lane & 15, hi = lane >> 4;
  int grp = wave >> 2;                      // 0: long tile, 1: short tile
  int qblk_w = grp ? pi : (31 - pi);
  int qb0 = qblk_w * 64;
  int nkb = 32 - pi;                        // loop length = long tile's KV count
  const u16* qbase = q + (size_t)bh * 2048 * 64;
  const u16* kbase = k + (size_t)bh * 2048 * 64;
  const u16* vbase = vt + (size_t)bh * 64 * 2048;

  int srow = tid >> 3;
  int ssl = (tid & 7) ^ (srow & 7);         // both-sides XOR swizzle
  int kOff = srow * 64 + ssl * 8;
  int vOff = srow * 2048 + ssl * 8;

  int qrow = qb0 + (wave & 3) * 16 + lo;
  bf16x8 qf0 = *(const bf16x8*)(qbase + (size_t)qrow * 64 + hi * 8);
  bf16x8 qf1 = *(const bf16x8*)(qbase + (size_t)qrow * 64 + 32 + hi * 8);

  float l_r = 0.0f;
  f32x4 of[4] = {};
  u16* Pw = Ps[wave];

  auto stage = [&](int b, int kb) {
    gload_lds16(kbase + (size_t)kb * 4096 + kOff, Ks[b] + wave * 512);
    gload_lds16(vbase + kb * 64 + vOff, Vs[b] + wave * 512);
  };

  stage(0, 0);
  __syncthreads();

  for (int kb = 0; kb < nkb; kb++) {
    int cur = kb & 1;
    if (kb + 1 < nkb) stage(cur ^ 1, kb + 1);
    if (kb <= qblk_w) {
      const u16* Kb = Ks[cur];
      const u16* Vb = Vs[cur];
      f32x4 s4[4] = {};
#pragma unroll
      for (int nt = 0; nt < 4; nt++) {
        int r = nt * 16 + lo, rw = r & 7;
        bf16x8 kf0 = *(const bf16x8*)(Kb + r * 64 + ((hi ^ rw) << 3));
        bf16x8 kf1 = *(const bf16x8*)(Kb + r * 64 + (((hi + 4) ^ rw) << 3));
        s4[nt] = MFMA16(kf0, qf0, s4[nt]);
        s4[nt] = MFMA16(kf1, qf1, s4[nt]);
      }
      float rs = 0.0f;
      bool diag = (kb == qblk_w);
#pragma unroll
      for (int nt = 0; nt < 4; nt++) {
        float e0, e1, e2, e3;
        if (diag) {
          int key = kb * 64 + nt * 16 + hi * 4;
          e0 = (key     > qrow) ? 0.0f : __builtin_amdgcn_exp2f(s4[nt][0]);
          e1 = (key + 1 > qrow) ? 0.0f : __builtin_amdgcn_exp2f(s4[nt][1]);
          e2 = (key + 2 > qrow) ? 0.0f : __builtin_amdgcn_exp2f(s4[nt][2]);
          e3 = (key + 3 > qrow) ? 0.0f : __builtin_amdgcn_exp2f(s4[nt][3]);
        } else {
          e0 = __builtin_amdgcn_exp2f(s4[nt][0]);
          e1 = __builtin_amdgcn_exp2f(s4[nt][1]);
          e2 = __builtin_amdgcn_exp2f(s4[nt][2]);
          e3 = __builtin_amdgcn_exp2f(s4[nt][3]);
        }
        rs += (e0 + e1) + (e2 + e3);
        u32x2 w;
        w.x = cvt_pk_bf16(e0, e1);
        w.y = cvt_pk_bf16(e2, e3);
        *(u32x2*)(Pw + lo * 72 + nt * 16 + hi * 4) = w;
      }
      rs += __shfl_xor(rs, 16);
      rs += __shfl_xor(rs, 32);
      l_r += rs;
      bf16x8 pb0 = *(const bf16x8*)(Pw + lo * 72 + hi * 8);
      bf16x8 pb1 = *(const bf16x8*)(Pw + lo * 72 + 32 + hi * 8);
#pragma unroll
      for (int et = 0; et < 4; et++) {
        int e = et * 16 + lo, ew = e & 7;
        bf16x8 v0 = *(const bf16x8*)(Vb + e * 64 + ((hi ^ ew) << 3));
        bf16x8 v1 = *(const bf16x8*)(Vb + e * 64 + (((hi + 4) ^ ew) << 3));
        of[et] = MFMA16(v0, pb0, of[et]);
        of[et] = MFMA16(v1, pb1, of[et]);
      }
    }
    __syncthreads();
  }
  int hh = bh & 15, bb = bh >> 4;
  float inv = 1.0f / l_r;
  size_t obase = ((size_t)(bb * 2048 + qrow)) * 1024 + hh * 64 + hi * 4;
#pragma unroll
  for (int et = 0; et < 4; et++) {
    u32x2 w;
    w.x = cvt_pk_bf16(of[et][0] * inv, of[et][1] * inv);
    w.y = cvt_pk_bf16(of[et][2] * inv, of[et][3] * inv);
    *(u32x2*)(o + obase + et * 16) = w;
  }
}

extern "C" void kernel_launch(void* const* d_in, const int* in_sizes, int n_in,
                              void* d_out, int out_size, void* d_ws, size_t ws_size,
                              hipStream_t stream) {
  const float* x = (const float*)d_in[0];
  const float* Wq = (const float*)d_in[1];
  const float* Wk = (const float*)d_in[2];
  const float* Wv = (const float*)d_in[3];
  const float* Wo = (const float*)d_in[4];
  const float* bo = (const float*)d_in[5];
  const float* W1 = (const float*)d_in[6];
  const float* b1 = (const float*)d_in[7];
  const float* W2 = (const float*)d_in[8];
  const float* b2 = (const float*)d_in[9];
  const float* g1 = (const float*)d_in[10];
  const float* be1 = (const float*)d_in[11];
  const float* g2 = (const float*)d_in[12];
  const float* be2 = (const float*)d_in[13];
  float* out = (float*)d_out;
  char* ws = (char*)d_ws;
  const size_t MB = 1024ull * 1024ull;

  // workspace map (72MB peak), all transposes materialized up front:
  //  0- 8 : h (ln1) -> o (attn out)          [o dead after Wo gemm]
  //  8-14 : BtQKV [dead after QKV gemm]  -> h2 (ln2 out, 8-16)
  // 14-16 : WoT   [dead after Wo gemm]   -> (h2 tail)
  // 16-24 : W1T   [dead after FFN1]
  // 32-40 : qb    [dead after attn]      -> yb (32-64, FFN1 out)
  // 40-48 : kb    [dead after attn]
  // 48-56 : vtb   [dead after attn]
  // 64-72 : W2T   [dead after FFN2]
  u16* h = (u16*)(ws + 0);
  u16* o = h;
  u16* BtQKV = (u16*)(ws + 8 * MB);
  u16* WoT = (u16*)(ws + 14 * MB);
  u16* W1T = (u16*)(ws + 16 * MB);
  u16* W2T = (u16*)(ws + 64 * MB);
  u16* qb = (u16*)(ws + 32 * MB);
  u16* kb = (u16*)(ws + 40 * MB);
  u16* vtb = (u16*)(ws + 48 * MB);
  u16* h2 = (u16*)(ws + 8 * MB);
  u16* yb = (u16*)(ws + 32 * MB);

  // 1. prep: LN1 + all weight transposes (one launch)
  prep_kernel<<<16384, 256, 0, stream>>>(x, g1, be1, h, Wq, Wk, Wv, BtQKV,
                                         Wo, WoT, W1, W1T, W2, W2T);
  // 2. QKV projection: [4096][1024] x [3072][1024]^T, scatter epilogue (q pre-scaled)
  gemm8p<0><<<dim3(12, 16), 512, 0, stream>>>(h, BtQKV, 4096, 3072, 1024, 1024,
                                              (void*)qb, kb, vtb, nullptr);
  // 3. causal attention -> o (bf16 [B][T][D]); 16 mirrored-paired blocks x 32 bh
  attn_kernel<<<dim3(16, 32), 512, 0, stream>>>(qb, kb, vtb, o);
  // 4. Wo: out = x + o@Wo + bo (fp32), 128^2 8-wave tiles, 256 blocks
  gemm128<<<dim3(8, 32), 512, 0, stream>>>(o, WoT, 4096, 1024, 1024, bo, x, out);
  // 5. LN2: out -> h2 (bf16)
  ln_kernel<<<4096, 256, 0, stream>>>(out, g2, be2, h2);
  // 6. FFN1: y = relu(h2@W1 + b1) (bf16), 256^2 tiles
  gemm8p<2><<<dim3(16, 16), 512, 0, stream>>>(h2, W1T, 4096, 4096, 1024, 1024,
                                              (void*)yb, nullptr, nullptr, b1);
  // 7. FFN2: out = out + y@W2 + b2 (fp32), 128^2 8-wave tiles, K=4096
  gemm128<<<dim3(8, 32), 512, 0, stream>>>(yb, W2T, 4096, 1024, 4096, b2, out, out);
}